// Round 1
// baseline (6255.078 us; speedup 1.0000x reference)
//
#include <hip/hip_runtime.h>
#include <hip/hip_bf16.h>

#define HIDN 1152
#define NHEAD 16
#define HDIM 72
#define LTOK 1024
#define MTOK 2048
#define MLPM 3072

// ---------------- patch embed: x (B,4,64,64) -> hx (2048,1152) ----------------
__global__ __launch_bounds__(256) void k_patch(const float* __restrict__ x,
        const float* __restrict__ pw, const float* __restrict__ pb,
        float* __restrict__ h) {
    int m = blockIdx.x;            // 0..2047
    int b = m >> 10, l = m & 1023;
    int si = l >> 5, sj = l & 31;
    __shared__ float toks[16];
    int tid = threadIdx.x;
    if (tid < 16) {
        int pi = tid >> 3, pj = (tid >> 2) & 1, c = tid & 3;
        toks[tid] = x[((size_t)(b*4 + c)*64 + si*2 + pi)*64 + sj*2 + pj];
    }
    __syncthreads();
    for (int o = tid; o < HIDN; o += 256) {
        float acc = pb[o];
        #pragma unroll
        for (int kk = 0; kk < 16; ++kk) acc += toks[kk] * pw[kk*HIDN + o];
        h[(size_t)m*HIDN + o] = acc;
    }
}

// ---------------- timestep embedding -> silu(temb@w1+b1) ----------------
__global__ __launch_bounds__(256) void k_temb1(const float* __restrict__ t,
        const float* __restrict__ w1, const float* __restrict__ b1,
        float* __restrict__ temb1) {
    int b = blockIdx.x;
    int tid = threadIdx.x;
    __shared__ float emb[256];
    float tv = t[b];
    {
        int k = tid;
        if (k < 128) {
            float f = __expf(-logf(10000.f) * (float)k / 128.f);
            emb[k] = cosf(tv * f);
        } else {
            float f = __expf(-logf(10000.f) * (float)(k - 128) / 128.f);
            emb[k] = sinf(tv * f);
        }
    }
    __syncthreads();
    for (int o = tid; o < HIDN; o += 256) {
        float acc = b1[o];
        for (int k = 0; k < 256; ++k) acc += emb[k] * w1[(size_t)k*HIDN + o];
        temb1[b*HIDN + o] = acc / (1.f + __expf(-acc));   // silu
    }
}

// ---------------- c = temb1@w2+b2 + y_table[y]; csilu = silu(c) ----------------
__global__ __launch_bounds__(256) void k_csilu(const float* __restrict__ temb1,
        const float* __restrict__ w2, const float* __restrict__ b2,
        const float* __restrict__ ytab, const int* __restrict__ y,
        float* __restrict__ csilu) {
    int b = blockIdx.x; int tid = threadIdx.x;
    __shared__ float t1[HIDN];
    for (int k = tid; k < HIDN; k += 256) t1[k] = temb1[b*HIDN + k];
    __syncthreads();
    const float* yrow = ytab + (size_t)y[b]*HIDN;
    for (int o = tid; o < HIDN; o += 256) {
        float acc = b2[o] + yrow[o];
        for (int k = 0; k < HIDN; ++k) acc += t1[k] * w2[(size_t)k*HIDN + o];
        csilu[b*HIDN + o] = acc / (1.f + __expf(-acc));
    }
}

// ------- small conditioning GEMMs: out[(d*2+b)*N + j] = csilu[b]@W[d] + bias[d] -------
__global__ __launch_bounds__(256) void k_cond_mm(const float* __restrict__ csilu,
        const float* __restrict__ W, const float* __restrict__ bias,
        float* __restrict__ out, int N) {
    int jt = blockIdx.x, b = blockIdx.y, d = blockIdx.z;
    const float* Wd = W + (size_t)d*HIDN*N;
    const float* bd = bias + (size_t)d*N;
    float* od = out + ((size_t)d*2 + b)*N;
    __shared__ float cs[HIDN];
    int tid = threadIdx.x;
    for (int k = tid; k < HIDN; k += 256) cs[k] = csilu[b*HIDN + k];
    __syncthreads();
    int j = jt*256 + tid;
    float acc = bd[j];
    for (int k = 0; k < HIDN; ++k) acc += cs[k] * Wd[(size_t)k*N + j];
    od[j] = acc;
}

// ---------------- RoPE tables (1024, 72) ----------------
__global__ __launch_bounds__(256) void k_rope(float* __restrict__ cosb, float* __restrict__ sinb) {
    int idx = blockIdx.x*256 + threadIdx.x;
    if (idx >= LTOK*HDIM) return;
    int l = idx / HDIM, dd = idx % HDIM;
    int i = l >> 5, j = l & 31;
    int pos = (dd < 36) ? i : j;
    int mm = ((dd < 36) ? dd : dd - 36) >> 1;
    float f = __expf(-logf(10000.f) * (float)mm / 18.f);
    float fr = (float)pos * f;
    cosb[idx] = cosf(fr);
    sinb[idx] = sinf(fr);
}

// ---------------- rmsnorm * (1 + s_mod) ----------------
__global__ __launch_bounds__(256) void k_rms(const float* __restrict__ hx,
        const float* __restrict__ nw, const float* __restrict__ smod,
        float* __restrict__ outp) {
    int m = blockIdx.x; int b = m >> 10;
    int tid = threadIdx.x;
    const float* row = hx + (size_t)m*HIDN;
    float part = 0.f;
    for (int j = tid; j < HIDN; j += 256) { float v = row[j]; part += v*v; }
    for (int off = 32; off; off >>= 1) part += __shfl_xor(part, off);
    __shared__ float wsum[4];
    if ((tid & 63) == 0) wsum[tid >> 6] = part;
    __syncthreads();
    float rs = rsqrtf((wsum[0]+wsum[1]+wsum[2]+wsum[3]) * (1.f/HIDN) + 1e-6f);
    const float* sb = smod + (size_t)b*4608;
    float* orow = outp + (size_t)m*HIDN;
    for (int j = tid; j < HIDN; j += 256)
        orow[j] = row[j] * rs * nw[j] * (1.f + sb[j]);
}

// ---------------- fp32 tiled GEMM, 64x64x16, 256 threads, 4x4/thread ----------------
// EPI 0: C = A@W + bias      EPI 1: C += gate[b] * (A@W + bias)   (gate stride 4608)
template<int EPI>
__global__ __launch_bounds__(256) void k_gemm(const float* __restrict__ A,
        const float* __restrict__ W, const float* __restrict__ bias,
        float* __restrict__ C, int M, int N, int K,
        const float* __restrict__ gate) {
    __shared__ float As[16][64];
    __shared__ float Bs[16][64];
    int tid = threadIdx.x;
    int tx = tid & 15, ty = tid >> 4;
    int n0 = blockIdx.x * 64, m0 = blockIdx.y * 64;
    float acc[4][4] = {};
    int am = tid >> 2, ak = (tid & 3) * 4;
    int bk = tid >> 4, bn = (tid & 15) * 4;
    const float* Aptr = A + (size_t)(m0 + am)*K + ak;
    const float* Wptr = W + (size_t)bk*N + n0 + bn;
    for (int k0 = 0; k0 < K; k0 += 16) {
        float4 av = *(const float4*)(Aptr + k0);
        float4 bv = *(const float4*)(Wptr + (size_t)k0*N);
        As[ak+0][am] = av.x; As[ak+1][am] = av.y; As[ak+2][am] = av.z; As[ak+3][am] = av.w;
        *(float4*)&Bs[bk][bn] = bv;
        __syncthreads();
        #pragma unroll
        for (int k = 0; k < 16; ++k) {
            float4 aa = *(const float4*)&As[k][ty*4];
            float4 bb = *(const float4*)&Bs[k][tx*4];
            float a[4] = {aa.x, aa.y, aa.z, aa.w};
            float bq[4] = {bb.x, bb.y, bb.z, bb.w};
            #pragma unroll
            for (int i = 0; i < 4; ++i)
                #pragma unroll
                for (int j = 0; j < 4; ++j)
                    acc[i][j] += a[i] * bq[j];
        }
        __syncthreads();
    }
    #pragma unroll
    for (int i = 0; i < 4; ++i) {
        int row = m0 + ty*4 + i;
        int bi = row >> 10;
        float* crow = C + (size_t)row*N + n0 + tx*4;
        const float* brow = bias + n0 + tx*4;
        if (EPI == 0) {
            #pragma unroll
            for (int j = 0; j < 4; ++j) crow[j] = acc[i][j] + brow[j];
        } else {
            const float* g = gate + (size_t)bi*4608 + n0 + tx*4;
            #pragma unroll
            for (int j = 0; j < 4; ++j) crow[j] += g[j] * (acc[i][j] + brow[j]);
        }
    }
}

// ---------------- qkv split + RoPE: qkv (B,L,3456) -> q,k,v (B,NH,L,72) ----------------
__global__ __launch_bounds__(256) void k_ropesplit(const float* __restrict__ qkv,
        const float* __restrict__ cosb, const float* __restrict__ sinb,
        float* __restrict__ q, float* __restrict__ k, float* __restrict__ v) {
    int idx = blockIdx.x*256 + threadIdx.x;   // B*NH*L*36
    if (idx >= 2*NHEAD*LTOK*36) return;
    int dp = idx % 36;
    int l  = (idx / 36) % LTOK;
    int h  = (idx / (36*LTOK)) % NHEAD;
    int b  = idx / (36*LTOK*NHEAD);
    int d0 = dp*2;
    size_t src = (size_t)(b*LTOK + l)*3456 + h*HDIM + d0;
    float qe = qkv[src],        qo = qkv[src+1];
    float ke = qkv[src+HIDN],   ko = qkv[src+HIDN+1];
    float ve = qkv[src+2*HIDN], vo = qkv[src+2*HIDN+1];
    float ce = cosb[l*HDIM+d0], co = cosb[l*HDIM+d0+1];
    float se = sinb[l*HDIM+d0], so = sinb[l*HDIM+d0+1];
    size_t dst = (size_t)((b*NHEAD + h)*LTOK + l)*HDIM + d0;
    q[dst]   = qe*ce - qo*se;
    q[dst+1] = qo*co + qe*so;
    k[dst]   = ke*ce - ko*se;
    k[dst+1] = ko*co + ke*so;
    v[dst]   = ve;
    v[dst+1] = vo;
}

// ---------------- flash attention: 64 q-rows/block, 4 threads per row ----------------
__global__ __launch_bounds__(256) void k_attn(const float* __restrict__ q,
        const float* __restrict__ k, const float* __restrict__ v,
        float* __restrict__ o) {
    int blk = blockIdx.x;           // B*NH*16
    int qt = blk & 15;
    int h  = (blk >> 4) & 15;
    int b  = blk >> 8;
    const float scale = 0.117851130f; // 1/sqrt(72)
    const float* qb = q + ((size_t)(b*NHEAD + h)*LTOK + qt*64)*HDIM;
    const float* kb = k + (size_t)(b*NHEAD + h)*LTOK*HDIM;
    const float* vb = v + (size_t)(b*NHEAD + h)*LTOK*HDIM;
    __shared__ float qs[64][73];
    __shared__ float ks[16][72];
    __shared__ float vs[16][72];
    int tid = threadIdx.x;
    for (int idx = tid; idx < 64*72; idx += 256)
        qs[idx/72][idx%72] = qb[idx] * scale;
    __syncthreads();
    int r = tid >> 2, qd = tid & 3, d0 = qd*18;
    float qreg[18];
    #pragma unroll
    for (int i = 0; i < 18; ++i) qreg[i] = qs[r][d0+i];
    float mrun = -1e30f, srun = 0.f;
    float oacc[18] = {};
    for (int kt = 0; kt < 64; ++kt) {
        __syncthreads();
        for (int idx = tid; idx < 16*72; idx += 256) {
            ks[idx/72][idx%72] = kb[kt*16*72 + idx];
            vs[idx/72][idx%72] = vb[kt*16*72 + idx];
        }
        __syncthreads();
        float sc[16], cmax = -1e30f;
        #pragma unroll
        for (int kk = 0; kk < 16; ++kk) {
            float p = 0.f;
            #pragma unroll
            for (int i = 0; i < 18; ++i) p += qreg[i]*ks[kk][d0+i];
            p += __shfl_xor(p, 1);
            p += __shfl_xor(p, 2);
            sc[kk] = p;
            cmax = fmaxf(cmax, p);
        }
        float mn = fmaxf(mrun, cmax);
        float corr = __expf(mrun - mn);
        srun *= corr;
        #pragma unroll
        for (int i = 0; i < 18; ++i) oacc[i] *= corr;
        #pragma unroll
        for (int kk = 0; kk < 16; ++kk) {
            float p = __expf(sc[kk] - mn);
            srun += p;
            #pragma unroll
            for (int i = 0; i < 18; ++i) oacc[i] += p * vs[kk][d0+i];
        }
        mrun = mn;
    }
    float inv = 1.f / srun;
    float* op = o + (size_t)(b*LTOK + qt*64 + r)*HIDN + h*HDIM + d0;
    #pragma unroll
    for (int i = 0; i < 18; ++i) op[i] = oacc[i]*inv;
}

// ---------------- gated linear unit: mh = silu(x1)*x2 ----------------
__global__ __launch_bounds__(256) void k_glu(const float* __restrict__ x12, float* __restrict__ mh) {
    int idx = blockIdx.x*256 + threadIdx.x;   // 2048*3072
    int m = idx / MLPM, jj = idx % MLPM;
    float x1 = x12[(size_t)m*6144 + jj];
    float x2 = x12[(size_t)m*6144 + MLPM + jj];
    mh[idx] = x1 / (1.f + __expf(-x1)) * x2;
}

// ---------------- final norm + linear + unpatchify ----------------
__global__ __launch_bounds__(256) void k_final(const float* __restrict__ hx,
        const float* __restrict__ fnw, const float* __restrict__ fmod,
        const float* __restrict__ flw, const float* __restrict__ flb,
        float* __restrict__ out) {
    int m = blockIdx.x; int b = m >> 10, l = m & 1023;
    int tid = threadIdx.x;
    const float* row = hx + (size_t)m*HIDN;
    float part = 0.f;
    for (int j = tid; j < HIDN; j += 256) { float v2 = row[j]; part += v2*v2; }
    for (int off = 32; off; off >>= 1) part += __shfl_xor(part, off);
    __shared__ float wsum[4];
    __shared__ float hfs[HIDN];
    __shared__ float red[4][16];
    if ((tid & 63) == 0) wsum[tid >> 6] = part;
    __syncthreads();
    float rs = rsqrtf((wsum[0]+wsum[1]+wsum[2]+wsum[3]) * (1.f/HIDN) + 1e-6f);
    const float* fm = fmod + (size_t)b*2304;
    for (int j = tid; j < HIDN; j += 256)
        hfs[j] = row[j] * rs * fnw[j] * (1.f + fm[HIDN + j]) + fm[j];
    __syncthreads();
    float pacc[16] = {};
    for (int j = tid; j < HIDN; j += 256) {
        float hv = hfs[j];
        #pragma unroll
        for (int kk = 0; kk < 16; ++kk) pacc[kk] += hv * flw[j*16 + kk];
    }
    #pragma unroll
    for (int kk = 0; kk < 16; ++kk)
        for (int off = 32; off; off >>= 1) pacc[kk] += __shfl_xor(pacc[kk], off);
    if ((tid & 63) == 0) {
        int w = tid >> 6;
        #pragma unroll
        for (int kk = 0; kk < 16; ++kk) red[w][kk] = pacc[kk];
    }
    __syncthreads();
    if (tid < 16) {
        float val = red[0][tid] + red[1][tid] + red[2][tid] + red[3][tid] + flb[tid];
        int pi = tid >> 3, pj = (tid >> 2) & 1, c = tid & 3;
        int si = l >> 5, sj = l & 31;
        out[((size_t)(b*4 + c)*64 + si*2 + pi)*64 + sj*2 + pj] = val;
    }
}

extern "C" void kernel_launch(void* const* d_in, const int* in_sizes, int n_in,
                              void* d_out, int out_size, void* d_ws, size_t ws_size,
                              hipStream_t stream) {
    const float* x        = (const float*)d_in[0];
    const float* t        = (const float*)d_in[1];
    const int*   y        = (const int*)  d_in[2];
    const float* patch_w  = (const float*)d_in[3];
    const float* patch_b  = (const float*)d_in[4];
    const float* t_w1     = (const float*)d_in[5];
    const float* t_b1     = (const float*)d_in[6];
    const float* t_w2     = (const float*)d_in[7];
    const float* t_b2     = (const float*)d_in[8];
    const float* y_table  = (const float*)d_in[9];
    const float* norm1_w  = (const float*)d_in[10];
    const float* qkv_w    = (const float*)d_in[11];
    const float* qkv_b    = (const float*)d_in[12];
    const float* out_w    = (const float*)d_in[13];
    const float* out_b    = (const float*)d_in[14];
    const float* norm2_w  = (const float*)d_in[15];
    const float* mlp_w12  = (const float*)d_in[16];
    const float* mlp_b12  = (const float*)d_in[17];
    const float* mlp_w3   = (const float*)d_in[18];
    const float* mlp_b3   = (const float*)d_in[19];
    const float* adaln_w  = (const float*)d_in[20];
    const float* adaln_b  = (const float*)d_in[21];
    const float* fnorm_w  = (const float*)d_in[22];
    const float* fadaln_w = (const float*)d_in[23];
    const float* fadaln_b = (const float*)d_in[24];
    const float* flin_w   = (const float*)d_in[25];
    const float* flin_b   = (const float*)d_in[26];

    float* ws   = (float*)d_ws;
    float* hx    = ws;                  // 2048*1152
    float* hmod  = ws + 2359296;        // 2048*1152; also o, hmod2
    float* qkvb  = ws + 4718592;        // 2048*6144 max; qkv and x12 share
    float* qb    = ws + 17301504;       // 2048*1152
    float* kb    = ws + 19660800;       // 2048*1152
    float* vb    = ws + 22020096;       // 2048*1152
    float* mh    = qb;                  // 2048*3072 aliases q/k (consumed before rewrite)
    float* temb1 = ws + 24379392;       // 2*1152
    float* csilu = temb1 + 2304;        // 2*1152
    float* modb  = csilu + 2304;        // [4][2][4608]
    float* fmod  = modb + 36864;        // [2][2304]
    float* cosb  = fmod + 4608;         // 1024*72
    float* sinb  = cosb + 73728;        // 1024*72
    // total: 24,572,928 floats = 98.3 MB

    k_patch<<<2048, 256, 0, stream>>>(x, patch_w, patch_b, hx);
    k_temb1<<<2, 256, 0, stream>>>(t, t_w1, t_b1, temb1);
    k_csilu<<<2, 256, 0, stream>>>(temb1, t_w2, t_b2, y_table, y, csilu);
    k_cond_mm<<<dim3(18,2,4), 256, 0, stream>>>(csilu, adaln_w, adaln_b, modb, 4608);
    k_cond_mm<<<dim3(9,2,1), 256, 0, stream>>>(csilu, fadaln_w, fadaln_b, fmod, 2304);
    k_rope<<<288, 256, 0, stream>>>(cosb, sinb);

    for (int d = 0; d < 4; ++d) {
        const float* modd = modb + (size_t)d*2*4608;
        k_rms<<<2048, 256, 0, stream>>>(hx, norm1_w + d*HIDN, modd + 0*HIDN, hmod);
        k_gemm<0><<<dim3(54, 32), 256, 0, stream>>>(hmod, qkv_w + (size_t)d*HIDN*3456,
                qkv_b + d*3456, qkvb, MTOK, 3456, HIDN, nullptr);
        k_ropesplit<<<4608, 256, 0, stream>>>(qkvb, cosb, sinb, qb, kb, vb);
        k_attn<<<512, 256, 0, stream>>>(qb, kb, vb, hmod);
        k_gemm<1><<<dim3(18, 32), 256, 0, stream>>>(hmod, out_w + (size_t)d*HIDN*HIDN,
                out_b + d*HIDN, hx, MTOK, HIDN, HIDN, modd + 1*HIDN);
        k_rms<<<2048, 256, 0, stream>>>(hx, norm2_w + d*HIDN, modd + 2*HIDN, hmod);
        k_gemm<0><<<dim3(96, 32), 256, 0, stream>>>(hmod, mlp_w12 + (size_t)d*HIDN*6144,
                mlp_b12 + d*6144, qkvb, MTOK, 6144, HIDN, nullptr);
        k_glu<<<24576, 256, 0, stream>>>(qkvb, mh);
        k_gemm<1><<<dim3(18, 32), 256, 0, stream>>>(mh, mlp_w3 + (size_t)d*MLPM*HIDN,
                mlp_b3 + d*HIDN, hx, MTOK, HIDN, MLPM, modd + 3*HIDN);
    }
    k_final<<<2048, 256, 0, stream>>>(hx, fnorm_w, fmod, flin_w, flin_b, (float*)d_out);
}

// Round 3
// 3676.363 us; speedup vs baseline: 1.7014x; 1.7014x over previous
//
#include <hip/hip_runtime.h>
#include <hip/hip_bf16.h>

#define HIDN 1152
#define NHEAD 16
#define HDIM 72
#define LTOK 1024
#define MTOK 2048
#define MLPM 3072

typedef short bf16x8 __attribute__((ext_vector_type(8)));
typedef float f32x4 __attribute__((ext_vector_type(4)));

__device__ __forceinline__ void gload16(const void* g, void* l) {
    __builtin_amdgcn_global_load_lds(
        (const __attribute__((address_space(1))) void*)g,
        (__attribute__((address_space(3))) void*)l,
        16, 0, 0);
}

// ---------------- patch embed: x (B,4,64,64) -> hx (2048,1152) ----------------
__global__ __launch_bounds__(256) void k_patch(const float* __restrict__ x,
        const float* __restrict__ pw, const float* __restrict__ pb,
        float* __restrict__ h) {
    int m = blockIdx.x;            // 0..2047
    int b = m >> 10, l = m & 1023;
    int si = l >> 5, sj = l & 31;
    __shared__ float toks[16];
    int tid = threadIdx.x;
    if (tid < 16) {
        int pi = tid >> 3, pj = (tid >> 2) & 1, c = tid & 3;
        toks[tid] = x[((size_t)(b*4 + c)*64 + si*2 + pi)*64 + sj*2 + pj];
    }
    __syncthreads();
    for (int o = tid; o < HIDN; o += 256) {
        float acc = pb[o];
        #pragma unroll
        for (int kk = 0; kk < 16; ++kk) acc += toks[kk] * pw[kk*HIDN + o];
        h[(size_t)m*HIDN + o] = acc;
    }
}

// ---------------- timestep embedding -> silu(temb@w1+b1) ----------------
__global__ __launch_bounds__(256) void k_temb1(const float* __restrict__ t,
        const float* __restrict__ w1, const float* __restrict__ b1,
        float* __restrict__ temb1) {
    int b = blockIdx.x;
    int tid = threadIdx.x;
    __shared__ float emb[256];
    float tv = t[b];
    {
        int k = tid;
        if (k < 128) {
            float f = __expf(-logf(10000.f) * (float)k / 128.f);
            emb[k] = cosf(tv * f);
        } else {
            float f = __expf(-logf(10000.f) * (float)(k - 128) / 128.f);
            emb[k] = sinf(tv * f);
        }
    }
    __syncthreads();
    for (int o = tid; o < HIDN; o += 256) {
        float acc = b1[o];
        for (int k = 0; k < 256; ++k) acc += emb[k] * w1[(size_t)k*HIDN + o];
        temb1[b*HIDN + o] = acc / (1.f + __expf(-acc));   // silu
    }
}

// ---------------- c = temb1@w2+b2 + y_table[y]; csilu = silu(c) ----------------
__global__ __launch_bounds__(256) void k_csilu(const float* __restrict__ temb1,
        const float* __restrict__ w2, const float* __restrict__ b2,
        const float* __restrict__ ytab, const int* __restrict__ y,
        float* __restrict__ csilu) {
    int b = blockIdx.x; int tid = threadIdx.x;
    __shared__ float t1[HIDN];
    for (int k = tid; k < HIDN; k += 256) t1[k] = temb1[b*HIDN + k];
    __syncthreads();
    const float* yrow = ytab + (size_t)y[b]*HIDN;
    for (int o = tid; o < HIDN; o += 256) {
        float acc = b2[o] + yrow[o];
        for (int k = 0; k < HIDN; ++k) acc += t1[k] * w2[(size_t)k*HIDN + o];
        csilu[b*HIDN + o] = acc / (1.f + __expf(-acc));
    }
}

// ------- small conditioning GEMMs: out[(d*2+b)*N + j] = csilu[b]@W[d] + bias[d] -------
__global__ __launch_bounds__(256) void k_cond_mm(const float* __restrict__ csilu,
        const float* __restrict__ W, const float* __restrict__ bias,
        float* __restrict__ out, int N) {
    int jt = blockIdx.x, b = blockIdx.y, d = blockIdx.z;
    const float* Wd = W + (size_t)d*HIDN*N;
    const float* bd = bias + (size_t)d*N;
    float* od = out + ((size_t)d*2 + b)*N;
    __shared__ float cs[HIDN];
    int tid = threadIdx.x;
    for (int k = tid; k < HIDN; k += 256) cs[k] = csilu[b*HIDN + k];
    __syncthreads();
    int j = jt*256 + tid;
    float acc = bd[j];
    for (int k = 0; k < HIDN; ++k) acc += cs[k] * Wd[(size_t)k*N + j];
    od[j] = acc;
}

// ---------------- RoPE tables (1024, 72) ----------------
__global__ __launch_bounds__(256) void k_rope(float* __restrict__ cosb, float* __restrict__ sinb) {
    int idx = blockIdx.x*256 + threadIdx.x;
    if (idx >= LTOK*HDIM) return;
    int l = idx / HDIM, dd = idx % HDIM;
    int i = l >> 5, j = l & 31;
    int pos = (dd < 36) ? i : j;
    int mm = ((dd < 36) ? dd : dd - 36) >> 1;
    float f = __expf(-logf(10000.f) * (float)mm / 18.f);
    float fr = (float)pos * f;
    cosb[idx] = cosf(fr);
    sinb[idx] = sinf(fr);
}

// ---------------- rmsnorm * (1 + s_mod) -> bf16 ----------------
__global__ __launch_bounds__(256) void k_rms(const float* __restrict__ hx,
        const float* __restrict__ nw, const float* __restrict__ smod,
        __hip_bfloat16* __restrict__ outp) {
    int m = blockIdx.x; int b = m >> 10;
    int tid = threadIdx.x;
    const float* row = hx + (size_t)m*HIDN;
    float part = 0.f;
    for (int j = tid; j < HIDN; j += 256) { float v = row[j]; part += v*v; }
    for (int off = 32; off; off >>= 1) part += __shfl_xor(part, off);
    __shared__ float wsum[4];
    if ((tid & 63) == 0) wsum[tid >> 6] = part;
    __syncthreads();
    float rs = rsqrtf((wsum[0]+wsum[1]+wsum[2]+wsum[3]) * (1.f/HIDN) + 1e-6f);
    const float* sb = smod + (size_t)b*4608;
    __hip_bfloat16* orow = outp + (size_t)m*HIDN;
    for (int j = tid; j < HIDN; j += 256)
        orow[j] = __float2bfloat16(row[j] * rs * nw[j] * (1.f + sb[j]));
}

// ---------------- weight cast+transpose: W [K][N] fp32 -> Wt [N][K] bf16 ----------------
__global__ __launch_bounds__(256) void k_castT(const float* __restrict__ W,
        __hip_bfloat16* __restrict__ Wt, int K, int N) {
    __shared__ float tile[32][33];
    int n0 = blockIdx.x*32, k0 = blockIdx.y*32;
    int tx = threadIdx.x, ty = threadIdx.y;   // 32, 8
    for (int i = ty; i < 32; i += 8)
        tile[i][tx] = W[(size_t)(k0+i)*N + n0 + tx];
    __syncthreads();
    for (int i = ty; i < 32; i += 8)
        Wt[(size_t)(n0+i)*K + k0 + tx] = __float2bfloat16(tile[tx][i]);
}

// ---------------- bf16 MFMA GEMM: A [M][K] bf16, Wt [N][K] bf16 ------
// 128x128 tile, BK=64, 4 waves (2x2), each wave 64x64 via 4x4 16x16x32 frags.
// Staging: one gload16 covers 64 lanes x 16B = 8 rows x 64 cols bf16 (1 KB).
// 16 segments of 8 rows fill the 128x64 tile; wave w does segs w*4..w*4+3.
// EPI 0: C = bf16(A@W^T + bias)    EPI 1: C(f32) += gate[b]*(A@W^T + bias)
template<int EPI, typename OutT>
__global__ __launch_bounds__(256) void k_gemm_bf16(
        const __hip_bfloat16* __restrict__ A,
        const __hip_bfloat16* __restrict__ Wt,
        const float* __restrict__ bias,
        OutT* __restrict__ C, int M, int N, int K,
        const float* __restrict__ gate) {
    __shared__ __hip_bfloat16 Asm[128*64];
    __shared__ __hip_bfloat16 Bsm[128*64];
    int tid = threadIdx.x;
    int lane = tid & 63, w = tid >> 6;
    int wr = w >> 1, wc = w & 1;
    int m0 = blockIdx.y * 128, n0 = blockIdx.x * 128;
    f32x4 acc[4][4] = {};
    const __hip_bfloat16* Ag = A  + (size_t)(m0 + (lane>>3))*K + (lane&7)*8;
    const __hip_bfloat16* Bg = Wt + (size_t)(n0 + (lane>>3))*K + (lane&7)*8;
    for (int k0 = 0; k0 < K; k0 += 64) {
        #pragma unroll
        for (int i = 0; i < 4; ++i) {
            int seg = w*4 + i;   // 0..15, wave-uniform; covers rows seg*8..seg*8+7
            gload16(Ag + (size_t)(seg*8)*K + k0, (char*)Asm + seg*1024);
            gload16(Bg + (size_t)(seg*8)*K + k0, (char*)Bsm + seg*1024);
        }
        __syncthreads();
        #pragma unroll
        for (int kk = 0; kk < 2; ++kk) {
            bf16x8 af[4], bfr[4];
            #pragma unroll
            for (int m = 0; m < 4; ++m) {
                int row = wr*64 + m*16 + (lane&15);
                af[m] = *(const bf16x8*)(Asm + row*64 + kk*32 + (lane>>4)*8);
            }
            #pragma unroll
            for (int n = 0; n < 4; ++n) {
                int col = wc*64 + n*16 + (lane&15);
                bfr[n] = *(const bf16x8*)(Bsm + col*64 + kk*32 + (lane>>4)*8);
            }
            #pragma unroll
            for (int m = 0; m < 4; ++m)
                #pragma unroll
                for (int n = 0; n < 4; ++n)
                    acc[m][n] = __builtin_amdgcn_mfma_f32_16x16x32_bf16(af[m], bfr[n], acc[m][n], 0, 0, 0);
        }
        __syncthreads();
    }
    int r0 = (lane >> 4) * 4;
    int ccol = lane & 15;
    #pragma unroll
    for (int m = 0; m < 4; ++m) {
        #pragma unroll
        for (int rr = 0; rr < 4; ++rr) {
            int row = m0 + wr*64 + m*16 + r0 + rr;
            int bi = row >> 10;
            #pragma unroll
            for (int n = 0; n < 4; ++n) {
                int col = n0 + wc*64 + n*16 + ccol;
                float val = acc[m][n][rr] + bias[col];
                if (EPI == 0) {
                    C[(size_t)row*N + col] = (OutT)__float2bfloat16(val);
                } else {
                    ((float*)C)[(size_t)row*N + col] += gate[(size_t)bi*4608 + col] * val;
                }
            }
        }
    }
}

// ------- qkv split + RoPE: qkv (B,L,3456) bf16 -> q,k,v (B,NH,L,72) bf16 -------
__global__ __launch_bounds__(256) void k_ropesplit(const __hip_bfloat16* __restrict__ qkv,
        const float* __restrict__ cosb, const float* __restrict__ sinb,
        __hip_bfloat16* __restrict__ q, __hip_bfloat16* __restrict__ k,
        __hip_bfloat16* __restrict__ v) {
    int idx = blockIdx.x*256 + threadIdx.x;   // B*NH*L*36
    if (idx >= 2*NHEAD*LTOK*36) return;
    int dp = idx % 36;
    int l  = (idx / 36) % LTOK;
    int h  = (idx / (36*LTOK)) % NHEAD;
    int b  = idx / (36*LTOK*NHEAD);
    int d0 = dp*2;
    size_t src = (size_t)(b*LTOK + l)*3456 + h*HDIM + d0;
    float qe = __bfloat162float(qkv[src]),        qo = __bfloat162float(qkv[src+1]);
    float ke = __bfloat162float(qkv[src+HIDN]),   ko = __bfloat162float(qkv[src+HIDN+1]);
    float ce = cosb[l*HDIM+d0], co = cosb[l*HDIM+d0+1];
    float se = sinb[l*HDIM+d0], so = sinb[l*HDIM+d0+1];
    size_t dst = (size_t)((b*NHEAD + h)*LTOK + l)*HDIM + d0;
    q[dst]   = __float2bfloat16(qe*ce - qo*se);
    q[dst+1] = __float2bfloat16(qo*co + qe*so);
    k[dst]   = __float2bfloat16(ke*ce - ko*se);
    k[dst+1] = __float2bfloat16(ko*co + ke*so);
    v[dst]   = qkv[src+2*HIDN];
    v[dst+1] = qkv[src+2*HIDN+1];
}

// ------- flash attention: 64 q-rows/block, 4 threads per row, bf16 in -> bf16 out -------
__global__ __launch_bounds__(256) void k_attn(const __hip_bfloat16* __restrict__ q,
        const __hip_bfloat16* __restrict__ k, const __hip_bfloat16* __restrict__ v,
        __hip_bfloat16* __restrict__ o) {
    int blk = blockIdx.x;           // B*NH*16
    int qt = blk & 15;
    int h  = (blk >> 4) & 15;
    int b  = blk >> 8;
    const float scale = 0.117851130f; // 1/sqrt(72)
    const __hip_bfloat16* qb = q + ((size_t)(b*NHEAD + h)*LTOK + qt*64)*HDIM;
    const __hip_bfloat16* kb = k + (size_t)(b*NHEAD + h)*LTOK*HDIM;
    const __hip_bfloat16* vb = v + (size_t)(b*NHEAD + h)*LTOK*HDIM;
    __shared__ float qs[64][73];
    __shared__ float ks[16][72];
    __shared__ float vs[16][72];
    int tid = threadIdx.x;
    for (int idx = tid; idx < 64*72; idx += 256)
        qs[idx/72][idx%72] = __bfloat162float(qb[idx]) * scale;
    __syncthreads();
    int r = tid >> 2, qd = tid & 3, d0 = qd*18;
    float qreg[18];
    #pragma unroll
    for (int i = 0; i < 18; ++i) qreg[i] = qs[r][d0+i];
    float mrun = -1e30f, srun = 0.f;
    float oacc[18] = {};
    for (int kt = 0; kt < 64; ++kt) {
        __syncthreads();
        for (int idx = tid; idx < 16*72; idx += 256) {
            ks[idx/72][idx%72] = __bfloat162float(kb[kt*16*72 + idx]);
            vs[idx/72][idx%72] = __bfloat162float(vb[kt*16*72 + idx]);
        }
        __syncthreads();
        float sc[16], cmax = -1e30f;
        #pragma unroll
        for (int kk = 0; kk < 16; ++kk) {
            float p = 0.f;
            #pragma unroll
            for (int i = 0; i < 18; ++i) p += qreg[i]*ks[kk][d0+i];
            p += __shfl_xor(p, 1);
            p += __shfl_xor(p, 2);
            sc[kk] = p;
            cmax = fmaxf(cmax, p);
        }
        float mn = fmaxf(mrun, cmax);
        float corr = __expf(mrun - mn);
        srun *= corr;
        #pragma unroll
        for (int i = 0; i < 18; ++i) oacc[i] *= corr;
        #pragma unroll
        for (int kk = 0; kk < 16; ++kk) {
            float p = __expf(sc[kk] - mn);
            srun += p;
            #pragma unroll
            for (int i = 0; i < 18; ++i) oacc[i] += p * vs[kk][d0+i];
        }
        mrun = mn;
    }
    float inv = 1.f / srun;
    __hip_bfloat16* op = o + (size_t)(b*LTOK + qt*64 + r)*HIDN + h*HDIM + d0;
    #pragma unroll
    for (int i = 0; i < 18; ++i) op[i] = __float2bfloat16(oacc[i]*inv);
}

// ---------------- gated linear unit: mh = silu(x1)*x2 (bf16 in/out) ----------------
__global__ __launch_bounds__(256) void k_glu(const __hip_bfloat16* __restrict__ x12,
        __hip_bfloat16* __restrict__ mh) {
    int idx = blockIdx.x*256 + threadIdx.x;   // 2048*3072
    int m = idx / MLPM, jj = idx % MLPM;
    float x1 = __bfloat162float(x12[(size_t)m*6144 + jj]);
    float x2 = __bfloat162float(x12[(size_t)m*6144 + MLPM + jj]);
    mh[idx] = __float2bfloat16(x1 / (1.f + __expf(-x1)) * x2);
}

// ---------------- final norm + linear + unpatchify ----------------
__global__ __launch_bounds__(256) void k_final(const float* __restrict__ hx,
        const float* __restrict__ fnw, const float* __restrict__ fmod,
        const float* __restrict__ flw, const float* __restrict__ flb,
        float* __restrict__ out) {
    int m = blockIdx.x; int b = m >> 10, l = m & 1023;
    int tid = threadIdx.x;
    const float* row = hx + (size_t)m*HIDN;
    float part = 0.f;
    for (int j = tid; j < HIDN; j += 256) { float v2 = row[j]; part += v2*v2; }
    for (int off = 32; off; off >>= 1) part += __shfl_xor(part, off);
    __shared__ float wsum[4];
    __shared__ float hfs[HIDN];
    __shared__ float red[4][16];
    if ((tid & 63) == 0) wsum[tid >> 6] = part;
    __syncthreads();
    float rs = rsqrtf((wsum[0]+wsum[1]+wsum[2]+wsum[3]) * (1.f/HIDN) + 1e-6f);
    const float* fm = fmod + (size_t)b*2304;
    for (int j = tid; j < HIDN; j += 256)
        hfs[j] = row[j] * rs * fnw[j] * (1.f + fm[HIDN + j]) + fm[j];
    __syncthreads();
    float pacc[16] = {};
    for (int j = tid; j < HIDN; j += 256) {
        float hv = hfs[j];
        #pragma unroll
        for (int kk = 0; kk < 16; ++kk) pacc[kk] += hv * flw[j*16 + kk];
    }
    #pragma unroll
    for (int kk = 0; kk < 16; ++kk)
        for (int off = 32; off; off >>= 1) pacc[kk] += __shfl_xor(pacc[kk], off);
    if ((tid & 63) == 0) {
        int w = tid >> 6;
        #pragma unroll
        for (int kk = 0; kk < 16; ++kk) red[w][kk] = pacc[kk];
    }
    __syncthreads();
    if (tid < 16) {
        float val = red[0][tid] + red[1][tid] + red[2][tid] + red[3][tid] + flb[tid];
        int pi = tid >> 3, pj = (tid >> 2) & 1, c = tid & 3;
        int si = l >> 5, sj = l & 31;
        out[((size_t)(b*4 + c)*64 + si*2 + pi)*64 + sj*2 + pj] = val;
    }
}

extern "C" void kernel_launch(void* const* d_in, const int* in_sizes, int n_in,
                              void* d_out, int out_size, void* d_ws, size_t ws_size,
                              hipStream_t stream) {
    const float* x        = (const float*)d_in[0];
    const float* t        = (const float*)d_in[1];
    const int*   y        = (const int*)  d_in[2];
    const float* patch_w  = (const float*)d_in[3];
    const float* patch_b  = (const float*)d_in[4];
    const float* t_w1     = (const float*)d_in[5];
    const float* t_b1     = (const float*)d_in[6];
    const float* t_w2     = (const float*)d_in[7];
    const float* t_b2     = (const float*)d_in[8];
    const float* y_table  = (const float*)d_in[9];
    const float* norm1_w  = (const float*)d_in[10];
    const float* qkv_w    = (const float*)d_in[11];
    const float* qkv_b    = (const float*)d_in[12];
    const float* out_w    = (const float*)d_in[13];
    const float* out_b    = (const float*)d_in[14];
    const float* norm2_w  = (const float*)d_in[15];
    const float* mlp_w12  = (const float*)d_in[16];
    const float* mlp_b12  = (const float*)d_in[17];
    const float* mlp_w3   = (const float*)d_in[18];
    const float* mlp_b3   = (const float*)d_in[19];
    const float* adaln_w  = (const float*)d_in[20];
    const float* adaln_b  = (const float*)d_in[21];
    const float* fnorm_w  = (const float*)d_in[22];
    const float* fadaln_w = (const float*)d_in[23];
    const float* fadaln_b = (const float*)d_in[24];
    const float* flin_w   = (const float*)d_in[25];
    const float* flin_b   = (const float*)d_in[26];

    char* base = (char*)d_ws;
    float*          hx    = (float*)(base);                       //  9,437,184 B (2048x1152 f32)
    __hip_bfloat16* qkvbf = (__hip_bfloat16*)(base +  9437184);   // 25,165,824 B (2048x6144 bf16; qkv & x12)
    __hip_bfloat16* qbf   = (__hip_bfloat16*)(base + 34603008);   //  4,718,592 B
    __hip_bfloat16* kbf   = (__hip_bfloat16*)(base + 39321600);   //  4,718,592 B
    __hip_bfloat16* vbf   = (__hip_bfloat16*)(base + 44040192);   //  4,718,592 B
    __hip_bfloat16* hbf   = (__hip_bfloat16*)(base + 48758784);   //  4,718,592 B (2048x1152 bf16)
    __hip_bfloat16* mhbf  = qbf;                                  // 12,582,912 B aliases q/k/v (consumed)
    __hip_bfloat16* wtb   = (__hip_bfloat16*)(base + 53477376);   // 31,850,496 B (per-layer wt)
    float* temb1 = (float*)(base + 85327872);        // 9216 B
    float* csilu = (float*)(base + 85337088);        // 9216 B
    float* modb  = (float*)(base + 85346304);        // 147456 B [4][2][4608]
    float* fmod  = (float*)(base + 85493760);        // 18432 B  [2][2304]
    float* cosb  = (float*)(base + 85512192);        // 294912 B (1024x72)
    float* sinb  = (float*)(base + 85807104);        // 294912 B
    // total 86,102,016 B = 86.1 MB

    __hip_bfloat16* wt_qkv = wtb;                        // [3456][1152]
    __hip_bfloat16* wt_out = wt_qkv + 3456*1152;         // [1152][1152]
    __hip_bfloat16* wt_m12 = wt_out + 1152*1152;         // [6144][1152]
    __hip_bfloat16* wt_m3  = wt_m12 + 6144*1152;         // [1152][3072]

    k_patch<<<2048, 256, 0, stream>>>(x, patch_w, patch_b, hx);
    k_temb1<<<2, 256, 0, stream>>>(t, t_w1, t_b1, temb1);
    k_csilu<<<2, 256, 0, stream>>>(temb1, t_w2, t_b2, y_table, y, csilu);
    k_cond_mm<<<dim3(18,2,4), 256, 0, stream>>>(csilu, adaln_w, adaln_b, modb, 4608);
    k_cond_mm<<<dim3(9,2,1), 256, 0, stream>>>(csilu, fadaln_w, fadaln_b, fmod, 2304);
    k_rope<<<288, 256, 0, stream>>>(cosb, sinb);

    for (int d = 0; d < 4; ++d) {
        const float* modd = modb + (size_t)d*2*4608;
        // cast+transpose this layer's weights to bf16 [N][K]
        k_castT<<<dim3(108,36), dim3(32,8), 0, stream>>>(qkv_w  + (size_t)d*HIDN*3456, wt_qkv, HIDN, 3456);
        k_castT<<<dim3( 36,36), dim3(32,8), 0, stream>>>(out_w  + (size_t)d*HIDN*HIDN, wt_out, HIDN, HIDN);
        k_castT<<<dim3(192,36), dim3(32,8), 0, stream>>>(mlp_w12+ (size_t)d*HIDN*6144, wt_m12, HIDN, 6144);
        k_castT<<<dim3( 36,96), dim3(32,8), 0, stream>>>(mlp_w3 + (size_t)d*MLPM*HIDN, wt_m3,  MLPM, HIDN);

        k_rms<<<2048, 256, 0, stream>>>(hx, norm1_w + d*HIDN, modd + 0*HIDN, hbf);
        k_gemm_bf16<0, __hip_bfloat16><<<dim3(27,16), 256, 0, stream>>>(hbf, wt_qkv,
                qkv_b + d*3456, qkvbf, MTOK, 3456, HIDN, nullptr);
        k_ropesplit<<<4608, 256, 0, stream>>>(qkvbf, cosb, sinb, qbf, kbf, vbf);
        k_attn<<<512, 256, 0, stream>>>(qbf, kbf, vbf, hbf);
        k_gemm_bf16<1, float><<<dim3(9,16), 256, 0, stream>>>(hbf, wt_out,
                out_b + d*HIDN, hx, MTOK, HIDN, HIDN, modd + 1*HIDN);
        k_rms<<<2048, 256, 0, stream>>>(hx, norm2_w + d*HIDN, modd + 2*HIDN, hbf);
        k_gemm_bf16<0, __hip_bfloat16><<<dim3(48,16), 256, 0, stream>>>(hbf, wt_m12,
                mlp_b12 + d*6144, qkvbf, MTOK, 6144, HIDN, nullptr);
        k_glu<<<24576, 256, 0, stream>>>(qkvbf, mhbf);
        k_gemm_bf16<1, float><<<dim3(9,16), 256, 0, stream>>>(mhbf, wt_m3,
                mlp_b3 + d*HIDN, hx, MTOK, HIDN, MLPM, modd + 3*HIDN);
    }
    k_final<<<2048, 256, 0, stream>>>(hx, fnorm_w, fmod, flin_w, flin_b, (float*)d_out);
}

// Round 4
// 1811.697 us; speedup vs baseline: 3.4526x; 2.0292x over previous
//
#include <hip/hip_runtime.h>
#include <hip/hip_bf16.h>

#define HIDN 1152
#define NHEAD 16
#define HDIM 72
#define LTOK 1024
#define MTOK 2048
#define MLPM 3072

typedef short bf16x8 __attribute__((ext_vector_type(8)));
typedef float f32x4 __attribute__((ext_vector_type(4)));

__device__ __forceinline__ void gload16(const void* g, void* l) {
    __builtin_amdgcn_global_load_lds(
        (const __attribute__((address_space(1))) void*)g,
        (__attribute__((address_space(3))) void*)l,
        16, 0, 0);
}

// ---------------- patch embed: x (B,4,64,64) -> hx (2048,1152) ----------------
__global__ __launch_bounds__(256) void k_patch(const float* __restrict__ x,
        const float* __restrict__ pw, const float* __restrict__ pb,
        float* __restrict__ h) {
    int m = blockIdx.x;            // 0..2047
    int b = m >> 10, l = m & 1023;
    int si = l >> 5, sj = l & 31;
    __shared__ float toks[16];
    int tid = threadIdx.x;
    if (tid < 16) {
        int pi = tid >> 3, pj = (tid >> 2) & 1, c = tid & 3;
        toks[tid] = x[((size_t)(b*4 + c)*64 + si*2 + pi)*64 + sj*2 + pj];
    }
    __syncthreads();
    for (int o = tid; o < HIDN; o += 256) {
        float acc = pb[o];
        #pragma unroll
        for (int kk = 0; kk < 16; ++kk) acc += toks[kk] * pw[kk*HIDN + o];
        h[(size_t)m*HIDN + o] = acc;
    }
}

// ---------------- timestep embedding -> silu(temb@w1+b1) ----------------
__global__ __launch_bounds__(256) void k_temb1(const float* __restrict__ t,
        const float* __restrict__ w1, const float* __restrict__ b1,
        float* __restrict__ temb1) {
    int b = blockIdx.x;
    int tid = threadIdx.x;
    __shared__ float emb[256];
    float tv = t[b];
    {
        int k = tid;
        if (k < 128) {
            float f = __expf(-logf(10000.f) * (float)k / 128.f);
            emb[k] = cosf(tv * f);
        } else {
            float f = __expf(-logf(10000.f) * (float)(k - 128) / 128.f);
            emb[k] = sinf(tv * f);
        }
    }
    __syncthreads();
    for (int o = tid; o < HIDN; o += 256) {
        float acc = b1[o];
        for (int k = 0; k < 256; ++k) acc += emb[k] * w1[(size_t)k*HIDN + o];
        temb1[b*HIDN + o] = acc / (1.f + __expf(-acc));   // silu
    }
}

// ---------------- c = temb1@w2+b2 + y_table[y]; csilu = silu(c) ----------------
__global__ __launch_bounds__(256) void k_csilu(const float* __restrict__ temb1,
        const float* __restrict__ w2, const float* __restrict__ b2,
        const float* __restrict__ ytab, const int* __restrict__ y,
        float* __restrict__ csilu) {
    int b = blockIdx.x; int tid = threadIdx.x;
    __shared__ float t1[HIDN];
    for (int k = tid; k < HIDN; k += 256) t1[k] = temb1[b*HIDN + k];
    __syncthreads();
    const float* yrow = ytab + (size_t)y[b]*HIDN;
    for (int o = tid; o < HIDN; o += 256) {
        float acc = b2[o] + yrow[o];
        for (int k = 0; k < HIDN; ++k) acc += t1[k] * w2[(size_t)k*HIDN + o];
        csilu[b*HIDN + o] = acc / (1.f + __expf(-acc));
    }
}

// ------- small conditioning GEMMs: out[(d*2+b)*N + j] = csilu[b]@W[d] + bias[d] -------
__global__ __launch_bounds__(256) void k_cond_mm(const float* __restrict__ csilu,
        const float* __restrict__ W, const float* __restrict__ bias,
        float* __restrict__ out, int N) {
    int jt = blockIdx.x, b = blockIdx.y, d = blockIdx.z;
    const float* Wd = W + (size_t)d*HIDN*N;
    const float* bd = bias + (size_t)d*N;
    float* od = out + ((size_t)d*2 + b)*N;
    __shared__ float cs[HIDN];
    int tid = threadIdx.x;
    for (int k = tid; k < HIDN; k += 256) cs[k] = csilu[b*HIDN + k];
    __syncthreads();
    int j = jt*256 + tid;
    float acc = bd[j];
    for (int k = 0; k < HIDN; ++k) acc += cs[k] * Wd[(size_t)k*N + j];
    od[j] = acc;
}

// ---------------- RoPE tables (1024, 72) ----------------
__global__ __launch_bounds__(256) void k_rope(float* __restrict__ cosb, float* __restrict__ sinb) {
    int idx = blockIdx.x*256 + threadIdx.x;
    if (idx >= LTOK*HDIM) return;
    int l = idx / HDIM, dd = idx % HDIM;
    int i = l >> 5, j = l & 31;
    int pos = (dd < 36) ? i : j;
    int mm = ((dd < 36) ? dd : dd - 36) >> 1;
    float f = __expf(-logf(10000.f) * (float)mm / 18.f);
    float fr = (float)pos * f;
    cosb[idx] = cosf(fr);
    sinb[idx] = sinf(fr);
}

// ---------------- rmsnorm * (1 + s_mod) -> bf16 ----------------
__global__ __launch_bounds__(256) void k_rms(const float* __restrict__ hx,
        const float* __restrict__ nw, const float* __restrict__ smod,
        __hip_bfloat16* __restrict__ outp) {
    int m = blockIdx.x; int b = m >> 10;
    int tid = threadIdx.x;
    const float* row = hx + (size_t)m*HIDN;
    float part = 0.f;
    for (int j = tid; j < HIDN; j += 256) { float v = row[j]; part += v*v; }
    for (int off = 32; off; off >>= 1) part += __shfl_xor(part, off);
    __shared__ float wsum[4];
    if ((tid & 63) == 0) wsum[tid >> 6] = part;
    __syncthreads();
    float rs = rsqrtf((wsum[0]+wsum[1]+wsum[2]+wsum[3]) * (1.f/HIDN) + 1e-6f);
    const float* sb = smod + (size_t)b*4608;
    __hip_bfloat16* orow = outp + (size_t)m*HIDN;
    for (int j = tid; j < HIDN; j += 256)
        orow[j] = __float2bfloat16(row[j] * rs * nw[j] * (1.f + sb[j]));
}

// ---------------- weight cast+transpose: W [K][N] fp32 -> Wt [N][K] bf16 ----------------
__global__ __launch_bounds__(256) void k_castT(const float* __restrict__ W,
        __hip_bfloat16* __restrict__ Wt, int K, int N) {
    __shared__ float tile[32][33];
    int n0 = blockIdx.x*32, k0 = blockIdx.y*32;
    int tx = threadIdx.x, ty = threadIdx.y;   // 32, 8
    for (int i = ty; i < 32; i += 8)
        tile[i][tx] = W[(size_t)(k0+i)*N + n0 + tx];
    __syncthreads();
    for (int i = ty; i < 32; i += 8)
        Wt[(size_t)(n0+i)*K + k0 + tx] = __float2bfloat16(tile[tx][i]);
}

// ---------------- bf16 MFMA GEMM: A [M][K] bf16, Wt [N][K] bf16 ------
// 128x128 tile, BK=64, 4 waves (2x2), each wave 64x64 via 4x4 16x16x32 frags.
// EPI 0: C = bf16(A@W^T + bias)    EPI 1: C(f32) += gate[b]*(A@W^T + bias)
template<int EPI, typename OutT>
__global__ __launch_bounds__(256) void k_gemm_bf16(
        const __hip_bfloat16* __restrict__ A,
        const __hip_bfloat16* __restrict__ Wt,
        const float* __restrict__ bias,
        OutT* __restrict__ C, int M, int N, int K,
        const float* __restrict__ gate) {
    __shared__ __hip_bfloat16 Asm[128*64];
    __shared__ __hip_bfloat16 Bsm[128*64];
    int tid = threadIdx.x;
    int lane = tid & 63, w = tid >> 6;
    int wr = w >> 1, wc = w & 1;
    int m0 = blockIdx.y * 128, n0 = blockIdx.x * 128;
    f32x4 acc[4][4] = {};
    const __hip_bfloat16* Ag = A  + (size_t)(m0 + (lane>>3))*K + (lane&7)*8;
    const __hip_bfloat16* Bg = Wt + (size_t)(n0 + (lane>>3))*K + (lane&7)*8;
    for (int k0 = 0; k0 < K; k0 += 64) {
        #pragma unroll
        for (int i = 0; i < 4; ++i) {
            int seg = w*4 + i;   // 0..15, wave-uniform; covers rows seg*8..seg*8+7
            gload16(Ag + (size_t)(seg*8)*K + k0, (char*)Asm + seg*1024);
            gload16(Bg + (size_t)(seg*8)*K + k0, (char*)Bsm + seg*1024);
        }
        __syncthreads();
        #pragma unroll
        for (int kk = 0; kk < 2; ++kk) {
            bf16x8 af[4], bfr[4];
            #pragma unroll
            for (int m = 0; m < 4; ++m) {
                int row = wr*64 + m*16 + (lane&15);
                af[m] = *(const bf16x8*)(Asm + row*64 + kk*32 + (lane>>4)*8);
            }
            #pragma unroll
            for (int n = 0; n < 4; ++n) {
                int col = wc*64 + n*16 + (lane&15);
                bfr[n] = *(const bf16x8*)(Bsm + col*64 + kk*32 + (lane>>4)*8);
            }
            #pragma unroll
            for (int m = 0; m < 4; ++m)
                #pragma unroll
                for (int n = 0; n < 4; ++n)
                    acc[m][n] = __builtin_amdgcn_mfma_f32_16x16x32_bf16(af[m], bfr[n], acc[m][n], 0, 0, 0);
        }
        __syncthreads();
    }
    int r0 = (lane >> 4) * 4;
    int ccol = lane & 15;
    #pragma unroll
    for (int m = 0; m < 4; ++m) {
        #pragma unroll
        for (int rr = 0; rr < 4; ++rr) {
            int row = m0 + wr*64 + m*16 + r0 + rr;
            int bi = row >> 10;
            #pragma unroll
            for (int n = 0; n < 4; ++n) {
                int col = n0 + wc*64 + n*16 + ccol;
                float val = acc[m][n][rr] + bias[col];
                if (EPI == 0) {
                    C[(size_t)row*N + col] = (OutT)__float2bfloat16(val);
                } else {
                    ((float*)C)[(size_t)row*N + col] += gate[(size_t)bi*4608 + col] * val;
                }
            }
        }
    }
}

// ------- qkv split + RoPE: qkv (B,L,3456) bf16 -> q,k (B,NH,L,72); v TRANSPOSED (B,NH,72,L) -------
__global__ __launch_bounds__(256) void k_ropesplit(const __hip_bfloat16* __restrict__ qkv,
        const float* __restrict__ cosb, const float* __restrict__ sinb,
        __hip_bfloat16* __restrict__ q, __hip_bfloat16* __restrict__ k,
        __hip_bfloat16* __restrict__ v) {
    int idx = blockIdx.x*256 + threadIdx.x;   // B*NH*L*36
    if (idx >= 2*NHEAD*LTOK*36) return;
    int dp = idx % 36;
    int l  = (idx / 36) % LTOK;
    int h  = (idx / (36*LTOK)) % NHEAD;
    int b  = idx / (36*LTOK*NHEAD);
    int d0 = dp*2;
    size_t src = (size_t)(b*LTOK + l)*3456 + h*HDIM + d0;
    float qe = __bfloat162float(qkv[src]),        qo = __bfloat162float(qkv[src+1]);
    float ke = __bfloat162float(qkv[src+HIDN]),   ko = __bfloat162float(qkv[src+HIDN+1]);
    float ce = cosb[l*HDIM+d0], co = cosb[l*HDIM+d0+1];
    float se = sinb[l*HDIM+d0], so = sinb[l*HDIM+d0+1];
    size_t dst = (size_t)((b*NHEAD + h)*LTOK + l)*HDIM + d0;
    q[dst]   = __float2bfloat16(qe*ce - qo*se);
    q[dst+1] = __float2bfloat16(qo*co + qe*so);
    k[dst]   = __float2bfloat16(ke*ce - ko*se);
    k[dst+1] = __float2bfloat16(ko*co + ke*so);
    size_t vdst = ((size_t)(b*NHEAD + h)*HDIM + d0)*LTOK + l;
    v[vdst]        = qkv[src+2*HIDN];
    v[vdst+LTOK]   = qkv[src+2*HIDN+1];
}

// ------- MFMA flash attention: block = 64 q-rows of one head, 4 waves x 16 rows -------
// q,k: (B,NH,L,72) bf16; vt: (B,NH,72,L) bf16; o: (B,L,1152) bf16 at [.., h*72+d]
__global__ __launch_bounds__(256) void k_attn_mfma(
        const __hip_bfloat16* __restrict__ q,
        const __hip_bfloat16* __restrict__ k,
        const __hip_bfloat16* __restrict__ vt,
        __hip_bfloat16* __restrict__ o) {
    int blk = blockIdx.x;          // B*NH*16 = 512
    int qt = blk & 15, h = (blk >> 4) & 15, b = blk >> 8;
    const float scale = 0.117851130f;   // 1/sqrt(72)
    __shared__ __hip_bfloat16 Ksm[64*104];   // [key][d] stride 104 (208B, 16B-mult); d>=72 zero
    __shared__ __hip_bfloat16 Vsm[80*72];    // [d][key] stride 72 (144B); rows 72..79 zero
    __shared__ __hip_bfloat16 Psm[4][16*72]; // per-wave P, stride 72
    int tid = threadIdx.x, lane = tid & 63, w = tid >> 6;
    int l15 = lane & 15, g = lane >> 4;
    const __hip_bfloat16* qg = q  + ((size_t)(b*NHEAD + h)*LTOK + qt*64)*HDIM;
    const __hip_bfloat16* kg = k  + (size_t)(b*NHEAD + h)*LTOK*HDIM;
    const __hip_bfloat16* vg = vt + (size_t)(b*NHEAD + h)*HDIM*LTOK;

    // zero pad regions (persist: staging never writes them)
    {
        bf16x8 z = {};
        *(bf16x8*)(Ksm + (tid>>2)*104 + 72 + (tid&3)*8) = z;       // 64 rows x 4 segs
        if (tid < 72) *(bf16x8*)(Vsm + (72 + tid/9)*72 + (tid%9)*8) = z;
    }
    // stage Q (64 rows) into Ksm, pull frags to regs
    for (int i = tid; i < 576; i += 256) {
        int r = i/9, s = i%9;
        *(bf16x8*)(Ksm + r*104 + s*8) = *(const bf16x8*)(qg + r*HDIM + s*8);
    }
    __syncthreads();
    bf16x8 qf[3];
    #pragma unroll
    for (int c = 0; c < 3; ++c)
        qf[c] = *(const bf16x8*)(Ksm + (w*16 + l15)*104 + c*32 + g*8);
    __syncthreads();

    f32x4 oacc[5] = {};
    float mold[4] = {-1e30f, -1e30f, -1e30f, -1e30f};
    float lsum[4] = {};

    for (int kt = 0; kt < 16; ++kt) {
        for (int i = tid; i < 576; i += 256) {
            int r = i/9, s = i%9;
            *(bf16x8*)(Ksm + r*104 + s*8) = *(const bf16x8*)(kg + (size_t)(kt*64 + r)*HDIM + s*8);
        }
        for (int i = tid; i < 576; i += 256) {
            int r = i>>3, s = i&7;
            *(bf16x8*)(Vsm + r*72 + s*8) = *(const bf16x8*)(vg + (size_t)r*LTOK + kt*64 + s*8);
        }
        __syncthreads();
        // S = Q(16x96) @ K^T(96x64): 4 key-subtiles x 3 k-chunks
        f32x4 st[4] = {};
        #pragma unroll
        for (int t = 0; t < 4; ++t) {
            #pragma unroll
            for (int c = 0; c < 3; ++c) {
                bf16x8 kf = *(const bf16x8*)(Ksm + (t*16 + l15)*104 + c*32 + g*8);
                st[t] = __builtin_amdgcn_mfma_f32_16x16x32_bf16(qf[c], kf, st[t], 0, 0, 0);
            }
        }
        // online softmax; row r of this wave's tile lives in reg r across 16-lane group g
        #pragma unroll
        for (int r = 0; r < 4; ++r) {
            float mt = fmaxf(fmaxf(st[0][r], st[1][r]), fmaxf(st[2][r], st[3][r]));
            mt = fmaxf(mt, __shfl_xor(mt, 1));
            mt = fmaxf(mt, __shfl_xor(mt, 2));
            mt = fmaxf(mt, __shfl_xor(mt, 4));
            mt = fmaxf(mt, __shfl_xor(mt, 8));
            float mn = fmaxf(mold[r], mt);
            float corr = __expf((mold[r] - mn) * scale);
            mold[r] = mn;
            lsum[r] *= corr;
            #pragma unroll
            for (int dt = 0; dt < 5; ++dt) oacc[dt][r] *= corr;
            float rs = 0.f;
            #pragma unroll
            for (int t = 0; t < 4; ++t) {
                float p = __expf((st[t][r] - mn) * scale);
                rs += p;
                Psm[w][(g*4 + r)*72 + t*16 + l15] = __float2bfloat16(p);
            }
            rs += __shfl_xor(rs, 1);
            rs += __shfl_xor(rs, 2);
            rs += __shfl_xor(rs, 4);
            rs += __shfl_xor(rs, 8);
            lsum[r] += rs;
        }
        // O += P(16x64) @ V(64x80): 5 d-subtiles x 2 k-chunks
        bf16x8 pa[2];
        #pragma unroll
        for (int c = 0; c < 2; ++c)
            pa[c] = *(const bf16x8*)(&Psm[w][l15*72 + c*32 + g*8]);
        #pragma unroll
        for (int dt = 0; dt < 5; ++dt) {
            #pragma unroll
            for (int c = 0; c < 2; ++c) {
                bf16x8 vf = *(const bf16x8*)(Vsm + (dt*16 + l15)*72 + c*32 + g*8);
                oacc[dt] = __builtin_amdgcn_mfma_f32_16x16x32_bf16(pa[c], vf, oacc[dt], 0, 0, 0);
            }
        }
        __syncthreads();
    }
    #pragma unroll
    for (int r = 0; r < 4; ++r) {
        float inv = 1.f / lsum[r];
        int row = qt*64 + w*16 + g*4 + r;
        __hip_bfloat16* op = o + ((size_t)b*LTOK + row)*HIDN + h*HDIM;
        #pragma unroll
        for (int dt = 0; dt < 5; ++dt) {
            int d = dt*16 + l15;
            if (d < HDIM) op[d] = __float2bfloat16(oacc[dt][r] * inv);
        }
    }
}

// ---------------- gated linear unit: mh = silu(x1)*x2 (bf16 in/out) ----------------
__global__ __launch_bounds__(256) void k_glu(const __hip_bfloat16* __restrict__ x12,
        __hip_bfloat16* __restrict__ mh) {
    int idx = blockIdx.x*256 + threadIdx.x;   // 2048*3072
    int m = idx / MLPM, jj = idx % MLPM;
    float x1 = __bfloat162float(x12[(size_t)m*6144 + jj]);
    float x2 = __bfloat162float(x12[(size_t)m*6144 + MLPM + jj]);
    mh[idx] = __float2bfloat16(x1 / (1.f + __expf(-x1)) * x2);
}

// ---------------- final norm + linear + unpatchify ----------------
__global__ __launch_bounds__(256) void k_final(const float* __restrict__ hx,
        const float* __restrict__ fnw, const float* __restrict__ fmod,
        const float* __restrict__ flw, const float* __restrict__ flb,
        float* __restrict__ out) {
    int m = blockIdx.x; int b = m >> 10, l = m & 1023;
    int tid = threadIdx.x;
    const float* row = hx + (size_t)m*HIDN;
    float part = 0.f;
    for (int j = tid; j < HIDN; j += 256) { float v2 = row[j]; part += v2*v2; }
    for (int off = 32; off; off >>= 1) part += __shfl_xor(part, off);
    __shared__ float wsum[4];
    __shared__ float hfs[HIDN];
    __shared__ float red[4][16];
    if ((tid & 63) == 0) wsum[tid >> 6] = part;
    __syncthreads();
    float rs = rsqrtf((wsum[0]+wsum[1]+wsum[2]+wsum[3]) * (1.f/HIDN) + 1e-6f);
    const float* fm = fmod + (size_t)b*2304;
    for (int j = tid; j < HIDN; j += 256)
        hfs[j] = row[j] * rs * fnw[j] * (1.f + fm[HIDN + j]) + fm[j];
    __syncthreads();
    float pacc[16] = {};
    for (int j = tid; j < HIDN; j += 256) {
        float hv = hfs[j];
        #pragma unroll
        for (int kk = 0; kk < 16; ++kk) pacc[kk] += hv * flw[j*16 + kk];
    }
    #pragma unroll
    for (int kk = 0; kk < 16; ++kk)
        for (int off = 32; off; off >>= 1) pacc[kk] += __shfl_xor(pacc[kk], off);
    if ((tid & 63) == 0) {
        int w = tid >> 6;
        #pragma unroll
        for (int kk = 0; kk < 16; ++kk) red[w][kk] = pacc[kk];
    }
    __syncthreads();
    if (tid < 16) {
        float val = red[0][tid] + red[1][tid] + red[2][tid] + red[3][tid] + flb[tid];
        int pi = tid >> 3, pj = (tid >> 2) & 1, c = tid & 3;
        int si = l >> 5, sj = l & 31;
        out[((size_t)(b*4 + c)*64 + si*2 + pi)*64 + sj*2 + pj] = val;
    }
}

extern "C" void kernel_launch(void* const* d_in, const int* in_sizes, int n_in,
                              void* d_out, int out_size, void* d_ws, size_t ws_size,
                              hipStream_t stream) {
    const float* x        = (const float*)d_in[0];
    const float* t        = (const float*)d_in[1];
    const int*   y        = (const int*)  d_in[2];
    const float* patch_w  = (const float*)d_in[3];
    const float* patch_b  = (const float*)d_in[4];
    const float* t_w1     = (const float*)d_in[5];
    const float* t_b1     = (const float*)d_in[6];
    const float* t_w2     = (const float*)d_in[7];
    const float* t_b2     = (const float*)d_in[8];
    const float* y_table  = (const float*)d_in[9];
    const float* norm1_w  = (const float*)d_in[10];
    const float* qkv_w    = (const float*)d_in[11];
    const float* qkv_b    = (const float*)d_in[12];
    const float* out_w    = (const float*)d_in[13];
    const float* out_b    = (const float*)d_in[14];
    const float* norm2_w  = (const float*)d_in[15];
    const float* mlp_w12  = (const float*)d_in[16];
    const float* mlp_b12  = (const float*)d_in[17];
    const float* mlp_w3   = (const float*)d_in[18];
    const float* mlp_b3   = (const float*)d_in[19];
    const float* adaln_w  = (const float*)d_in[20];
    const float* adaln_b  = (const float*)d_in[21];
    const float* fnorm_w  = (const float*)d_in[22];
    const float* fadaln_w = (const float*)d_in[23];
    const float* fadaln_b = (const float*)d_in[24];
    const float* flin_w   = (const float*)d_in[25];
    const float* flin_b   = (const float*)d_in[26];

    char* base = (char*)d_ws;
    float*          hx    = (float*)(base);                       //  9,437,184 B (2048x1152 f32)
    __hip_bfloat16* qkvbf = (__hip_bfloat16*)(base +  9437184);   // 25,165,824 B (2048x6144 bf16; qkv & x12)
    __hip_bfloat16* qbf   = (__hip_bfloat16*)(base + 34603008);   //  4,718,592 B
    __hip_bfloat16* kbf   = (__hip_bfloat16*)(base + 39321600);   //  4,718,592 B
    __hip_bfloat16* vbf   = (__hip_bfloat16*)(base + 44040192);   //  4,718,592 B (transposed (B,NH,72,L))
    __hip_bfloat16* hbf   = (__hip_bfloat16*)(base + 48758784);   //  4,718,592 B (2048x1152 bf16)
    __hip_bfloat16* mhbf  = qbf;                                  // 12,582,912 B aliases q/k/v (consumed)
    __hip_bfloat16* wtb   = (__hip_bfloat16*)(base + 53477376);   // 31,850,496 B (per-layer wt)
    float* temb1 = (float*)(base + 85327872);        // 9216 B
    float* csilu = (float*)(base + 85337088);        // 9216 B
    float* modb  = (float*)(base + 85346304);        // 147456 B [4][2][4608]
    float* fmod  = (float*)(base + 85493760);        // 18432 B  [2][2304]
    float* cosb  = (float*)(base + 85512192);        // 294912 B (1024x72)
    float* sinb  = (float*)(base + 85807104);        // 294912 B
    // total 86,102,016 B = 86.1 MB

    __hip_bfloat16* wt_qkv = wtb;                        // [3456][1152]
    __hip_bfloat16* wt_out = wt_qkv + 3456*1152;         // [1152][1152]
    __hip_bfloat16* wt_m12 = wt_out + 1152*1152;         // [6144][1152]
    __hip_bfloat16* wt_m3  = wt_m12 + 6144*1152;         // [1152][3072]

    k_patch<<<2048, 256, 0, stream>>>(x, patch_w, patch_b, hx);
    k_temb1<<<2, 256, 0, stream>>>(t, t_w1, t_b1, temb1);
    k_csilu<<<2, 256, 0, stream>>>(temb1, t_w2, t_b2, y_table, y, csilu);
    k_cond_mm<<<dim3(18,2,4), 256, 0, stream>>>(csilu, adaln_w, adaln_b, modb, 4608);
    k_cond_mm<<<dim3(9,2,1), 256, 0, stream>>>(csilu, fadaln_w, fadaln_b, fmod, 2304);
    k_rope<<<288, 256, 0, stream>>>(cosb, sinb);

    for (int d = 0; d < 4; ++d) {
        const float* modd = modb + (size_t)d*2*4608;
        // cast+transpose this layer's weights to bf16 [N][K]
        k_castT<<<dim3(108,36), dim3(32,8), 0, stream>>>(qkv_w  + (size_t)d*HIDN*3456, wt_qkv, HIDN, 3456);
        k_castT<<<dim3( 36,36), dim3(32,8), 0, stream>>>(out_w  + (size_t)d*HIDN*HIDN, wt_out, HIDN, HIDN);
        k_castT<<<dim3(192,36), dim3(32,8), 0, stream>>>(mlp_w12+ (size_t)d*HIDN*6144, wt_m12, HIDN, 6144);
        k_castT<<<dim3( 36,96), dim3(32,8), 0, stream>>>(mlp_w3 + (size_t)d*MLPM*HIDN, wt_m3,  MLPM, HIDN);

        k_rms<<<2048, 256, 0, stream>>>(hx, norm1_w + d*HIDN, modd + 0*HIDN, hbf);
        k_gemm_bf16<0, __hip_bfloat16><<<dim3(27,16), 256, 0, stream>>>(hbf, wt_qkv,
                qkv_b + d*3456, qkvbf, MTOK, 3456, HIDN, nullptr);
        k_ropesplit<<<4608, 256, 0, stream>>>(qkvbf, cosb, sinb, qbf, kbf, vbf);
        k_attn_mfma<<<512, 256, 0, stream>>>(qbf, kbf, vbf, hbf);
        k_gemm_bf16<1, float><<<dim3(9,16), 256, 0, stream>>>(hbf, wt_out,
                out_b + d*HIDN, hx, MTOK, HIDN, HIDN, modd + 1*HIDN);
        k_rms<<<2048, 256, 0, stream>>>(hx, norm2_w + d*HIDN, modd + 2*HIDN, hbf);
        k_gemm_bf16<0, __hip_bfloat16><<<dim3(48,16), 256, 0, stream>>>(hbf, wt_m12,
                mlp_b12 + d*6144, qkvbf, MTOK, 6144, HIDN, nullptr);
        k_glu<<<24576, 256, 0, stream>>>(qkvbf, mhbf);
        k_gemm_bf16<1, float><<<dim3(9,16), 256, 0, stream>>>(mhbf, wt_m3,
                mlp_b3 + d*HIDN, hx, MTOK, HIDN, MLPM, modd + 3*HIDN);
    }
    k_final<<<2048, 256, 0, stream>>>(hx, fnorm_w, fmod, flin_w, flin_b, (float*)d_out);
}

// Round 5
// 1330.647 us; speedup vs baseline: 4.7008x; 1.3615x over previous
//
#include <hip/hip_runtime.h>
#include <hip/hip_bf16.h>

#define HIDN 1152
#define NHEAD 16
#define HDIM 72
#define LTOK 1024
#define MTOK 2048
#define MLPM 3072

typedef short bf16x8 __attribute__((ext_vector_type(8)));
typedef float f32x4 __attribute__((ext_vector_type(4)));

__device__ __forceinline__ void gload16(const void* g, void* l) {
    __builtin_amdgcn_global_load_lds(
        (const __attribute__((address_space(1))) void*)g,
        (__attribute__((address_space(3))) void*)l,
        16, 0, 0);
}

// ---------------- patch embed: x (B,4,64,64) -> hx (2048,1152) ----------------
__global__ __launch_bounds__(256) void k_patch(const float* __restrict__ x,
        const float* __restrict__ pw, const float* __restrict__ pb,
        float* __restrict__ h) {
    int m = blockIdx.x;            // 0..2047
    int b = m >> 10, l = m & 1023;
    int si = l >> 5, sj = l & 31;
    __shared__ float toks[16];
    int tid = threadIdx.x;
    if (tid < 16) {
        int pi = tid >> 3, pj = (tid >> 2) & 1, c = tid & 3;
        toks[tid] = x[((size_t)(b*4 + c)*64 + si*2 + pi)*64 + sj*2 + pj];
    }
    __syncthreads();
    for (int o = tid; o < HIDN; o += 256) {
        float acc = pb[o];
        #pragma unroll
        for (int kk = 0; kk < 16; ++kk) acc += toks[kk] * pw[kk*HIDN + o];
        h[(size_t)m*HIDN + o] = acc;
    }
}

// ------- temb1 = silu(timestep_emb @ w1 + b1): grid (9,2), 2-way K-split in-block -------
__global__ __launch_bounds__(256) void k_temb1_v2(const float* __restrict__ t,
        const float* __restrict__ w1, const float* __restrict__ b1,
        float* __restrict__ temb1) {
    int jt = blockIdx.x, b = blockIdx.y;
    int tid = threadIdx.x;
    __shared__ float emb[256];
    __shared__ float red[128];
    float tv = t[b];
    if (tid < 128) { float f = __expf(-logf(10000.f) * (float)tid / 128.f);        emb[tid] = cosf(tv * f); }
    else           { float f = __expf(-logf(10000.f) * (float)(tid - 128) / 128.f); emb[tid] = sinf(tv * f); }
    __syncthreads();
    int o = jt*128 + (tid & 127), s = tid >> 7;
    float acc = 0.f;
    for (int k = s*128; k < s*128 + 128; ++k) acc += emb[k] * w1[(size_t)k*HIDN + o];
    if (s) red[tid & 127] = acc;
    __syncthreads();
    if (!s) {
        float v = acc + red[tid] + b1[o];
        temb1[b*HIDN + o] = v / (1.f + __expf(-v));
    }
}

// ------- csilu stage 1: partial[kz][b][o] = temb1[b] @ w2[kz-slice]: grid (9,4) -------
__global__ __launch_bounds__(256) void k_csilu_s1(const float* __restrict__ temb1,
        const float* __restrict__ w2, float* __restrict__ csilup) {
    int jt = blockIdx.x, kz = blockIdx.y;
    int tid = threadIdx.x;
    __shared__ float t1s[2][288];
    __shared__ float red[2][128];
    for (int i = tid; i < 576; i += 256)
        t1s[i/288][i%288] = temb1[(i/288)*HIDN + kz*288 + (i%288)];
    __syncthreads();
    int o = jt*128 + (tid & 127), s = tid >> 7;
    float a0 = 0.f, a1 = 0.f;
    for (int i = s*144; i < s*144 + 144; ++i) {
        float wv = w2[(size_t)(kz*288 + i)*HIDN + o];
        a0 += t1s[0][i]*wv; a1 += t1s[1][i]*wv;
    }
    if (s) { red[0][tid & 127] = a0; red[1][tid & 127] = a1; }
    __syncthreads();
    if (!s) {
        csilup[(kz*2 + 0)*HIDN + o] = a0 + red[0][tid];
        csilup[(kz*2 + 1)*HIDN + o] = a1 + red[1][tid];
    }
}

// ------- csilu stage 2: reduce + b2 + y_table[y] + silu: grid (9,2) x 128 -------
__global__ __launch_bounds__(128) void k_csilu_s2(const float* __restrict__ csilup,
        const float* __restrict__ b2, const float* __restrict__ ytab,
        const int* __restrict__ y, float* __restrict__ csilu) {
    int o = blockIdx.x*128 + threadIdx.x;
    int b = blockIdx.y;
    float acc = b2[o] + ytab[(size_t)y[b]*HIDN + o];
    #pragma unroll
    for (int kz = 0; kz < 4; ++kz) acc += csilup[(kz*2 + b)*HIDN + o];
    csilu[b*HIDN + o] = acc / (1.f + __expf(-acc));
}

// ------- conditioning stage 1: all adaln (4 layers x 4608) + fadaln (2304) cols -------
// col space c in [0,20736): c<18432 -> adaln layer c/4608; else fadaln. grid (162,4).
__global__ __launch_bounds__(256) void k_cond_s1(const float* __restrict__ csilu,
        const float* __restrict__ adaln_w, const float* __restrict__ fadaln_w,
        float* __restrict__ condp) {
    int ct = blockIdx.x, kz = blockIdx.y;
    int tid = threadIdx.x;
    int c0 = ct*128;
    const float* Wb; int rstride;
    if (c0 < 18432) { int d = c0/4608; Wb = adaln_w + (size_t)d*HIDN*4608 + (c0 % 4608); rstride = 4608; }
    else            { Wb = fadaln_w + (c0 - 18432); rstride = 2304; }
    __shared__ float cs[2][288];
    __shared__ float red[2][128];
    for (int i = tid; i < 576; i += 256)
        cs[i/288][i%288] = csilu[(i/288)*HIDN + kz*288 + (i%288)];
    __syncthreads();
    int o = tid & 127, s = tid >> 7;
    float a0 = 0.f, a1 = 0.f;
    for (int i = s*144; i < s*144 + 144; ++i) {
        float wv = Wb[(size_t)(kz*288 + i)*rstride + o];
        a0 += cs[0][i]*wv; a1 += cs[1][i]*wv;
    }
    if (s) { red[0][o] = a0; red[1][o] = a1; }
    __syncthreads();
    if (!s) {
        condp[((size_t)kz*2 + 0)*20736 + c0 + o] = a0 + red[0][o];
        condp[((size_t)kz*2 + 1)*20736 + c0 + o] = a1 + red[1][o];
    }
}

// ------- conditioning stage 2: reduce 4 partials + bias -> modb / fmod: grid (81,2) -------
__global__ __launch_bounds__(256) void k_cond_s2(const float* __restrict__ condp,
        const float* __restrict__ adaln_b, const float* __restrict__ fadaln_b,
        float* __restrict__ modb, float* __restrict__ fmod) {
    int c = blockIdx.x*256 + threadIdx.x;
    int b = blockIdx.y;
    float acc = 0.f;
    #pragma unroll
    for (int kz = 0; kz < 4; ++kz) acc += condp[((size_t)kz*2 + b)*20736 + c];
    if (c < 18432) {
        int d = c/4608, j = c%4608;
        modb[((size_t)d*2 + b)*4608 + j] = acc + adaln_b[(size_t)d*4608 + j];
    } else {
        int j = c - 18432;
        fmod[(size_t)b*2304 + j] = acc + fadaln_b[j];
    }
}

// ---------------- RoPE tables (1024, 72) ----------------
__global__ __launch_bounds__(256) void k_rope(float* __restrict__ cosb, float* __restrict__ sinb) {
    int idx = blockIdx.x*256 + threadIdx.x;
    if (idx >= LTOK*HDIM) return;
    int l = idx / HDIM, dd = idx % HDIM;
    int i = l >> 5, j = l & 31;
    int pos = (dd < 36) ? i : j;
    int mm = ((dd < 36) ? dd : dd - 36) >> 1;
    float f = __expf(-logf(10000.f) * (float)mm / 18.f);
    float fr = (float)pos * f;
    cosb[idx] = cosf(fr);
    sinb[idx] = sinf(fr);
}

// ---------------- rmsnorm * (1 + s_mod) -> bf16 ----------------
__global__ __launch_bounds__(256) void k_rms(const float* __restrict__ hx,
        const float* __restrict__ nw, const float* __restrict__ smod,
        __hip_bfloat16* __restrict__ outp) {
    int m = blockIdx.x; int b = m >> 10;
    int tid = threadIdx.x;
    const float* row = hx + (size_t)m*HIDN;
    float part = 0.f;
    for (int j = tid; j < HIDN; j += 256) { float v = row[j]; part += v*v; }
    for (int off = 32; off; off >>= 1) part += __shfl_xor(part, off);
    __shared__ float wsum[4];
    if ((tid & 63) == 0) wsum[tid >> 6] = part;
    __syncthreads();
    float rs = rsqrtf((wsum[0]+wsum[1]+wsum[2]+wsum[3]) * (1.f/HIDN) + 1e-6f);
    const float* sb = smod + (size_t)b*4608;
    __hip_bfloat16* orow = outp + (size_t)m*HIDN;
    for (int j = tid; j < HIDN; j += 256)
        orow[j] = __float2bfloat16(row[j] * rs * nw[j] * (1.f + sb[j]));
}

// ---------------- weight cast+transpose: W [K][N] fp32 -> Wt [N][K] bf16 ----------------
__global__ __launch_bounds__(256) void k_castT(const float* __restrict__ W,
        __hip_bfloat16* __restrict__ Wt, int K, int N) {
    __shared__ float tile[32][33];
    int n0 = blockIdx.x*32, k0 = blockIdx.y*32;
    int tx = threadIdx.x, ty = threadIdx.y;   // 32, 8
    for (int i = ty; i < 32; i += 8)
        tile[i][tx] = W[(size_t)(k0+i)*N + n0 + tx];
    __syncthreads();
    for (int i = ty; i < 32; i += 8)
        Wt[(size_t)(n0+i)*K + k0 + tx] = __float2bfloat16(tile[tx][i]);
}

// ---------------- bf16 MFMA GEMM 128x128: A [M][K], Wt [N][K] ------
// EPI 0: C = bf16(A@W^T + bias)    EPI 1: C(f32) += gate[b]*(A@W^T + bias)
template<int EPI, typename OutT>
__global__ __launch_bounds__(256) void k_gemm_bf16(
        const __hip_bfloat16* __restrict__ A,
        const __hip_bfloat16* __restrict__ Wt,
        const float* __restrict__ bias,
        OutT* __restrict__ C, int M, int N, int K,
        const float* __restrict__ gate) {
    __shared__ __hip_bfloat16 Asm[128*64];
    __shared__ __hip_bfloat16 Bsm[128*64];
    int tid = threadIdx.x;
    int lane = tid & 63, w = tid >> 6;
    int wr = w >> 1, wc = w & 1;
    int m0 = blockIdx.y * 128, n0 = blockIdx.x * 128;
    f32x4 acc[4][4] = {};
    const __hip_bfloat16* Ag = A  + (size_t)(m0 + (lane>>3))*K + (lane&7)*8;
    const __hip_bfloat16* Bg = Wt + (size_t)(n0 + (lane>>3))*K + (lane&7)*8;
    for (int k0 = 0; k0 < K; k0 += 64) {
        #pragma unroll
        for (int i = 0; i < 4; ++i) {
            int seg = w*4 + i;   // 0..15; 8 rows each
            gload16(Ag + (size_t)(seg*8)*K + k0, (char*)Asm + seg*1024);
            gload16(Bg + (size_t)(seg*8)*K + k0, (char*)Bsm + seg*1024);
        }
        __syncthreads();
        #pragma unroll
        for (int kk = 0; kk < 2; ++kk) {
            bf16x8 af[4], bfr[4];
            #pragma unroll
            for (int m = 0; m < 4; ++m) {
                int row = wr*64 + m*16 + (lane&15);
                af[m] = *(const bf16x8*)(Asm + row*64 + kk*32 + (lane>>4)*8);
            }
            #pragma unroll
            for (int n = 0; n < 4; ++n) {
                int col = wc*64 + n*16 + (lane&15);
                bfr[n] = *(const bf16x8*)(Bsm + col*64 + kk*32 + (lane>>4)*8);
            }
            #pragma unroll
            for (int m = 0; m < 4; ++m)
                #pragma unroll
                for (int n = 0; n < 4; ++n)
                    acc[m][n] = __builtin_amdgcn_mfma_f32_16x16x32_bf16(af[m], bfr[n], acc[m][n], 0, 0, 0);
        }
        __syncthreads();
    }
    int r0 = (lane >> 4) * 4;
    int ccol = lane & 15;
    #pragma unroll
    for (int m = 0; m < 4; ++m) {
        #pragma unroll
        for (int rr = 0; rr < 4; ++rr) {
            int row = m0 + wr*64 + m*16 + r0 + rr;
            int bi = row >> 10;
            #pragma unroll
            for (int n = 0; n < 4; ++n) {
                int col = n0 + wc*64 + n*16 + ccol;
                float val = acc[m][n][rr] + bias[col];
                if (EPI == 0) {
                    C[(size_t)row*N + col] = (OutT)__float2bfloat16(val);
                } else {
                    ((float*)C)[(size_t)row*N + col] += gate[(size_t)bi*4608 + col] * val;
                }
            }
        }
    }
}

// ------- bf16 MFMA GEMM 64x128 tile (higher occupancy for N=1152), EPI1 only -------
__global__ __launch_bounds__(256) void k_gemm64(
        const __hip_bfloat16* __restrict__ A,
        const __hip_bfloat16* __restrict__ Wt,
        const float* __restrict__ bias,
        float* __restrict__ C, int M, int N, int K,
        const float* __restrict__ gate) {
    __shared__ __hip_bfloat16 Asm[64*64];
    __shared__ __hip_bfloat16 Bsm[128*64];
    int tid = threadIdx.x;
    int lane = tid & 63, w = tid >> 6;
    int wr = w >> 1, wc = w & 1;
    int m0 = blockIdx.y * 64, n0 = blockIdx.x * 128;
    f32x4 acc[2][4] = {};
    const __hip_bfloat16* Ag = A  + (size_t)(m0 + (lane>>3))*K + (lane&7)*8;
    const __hip_bfloat16* Bg = Wt + (size_t)(n0 + (lane>>3))*K + (lane&7)*8;
    for (int k0 = 0; k0 < K; k0 += 64) {
        #pragma unroll
        for (int i = 0; i < 2; ++i) {
            int seg = w*2 + i;   // 0..7
            gload16(Ag + (size_t)(seg*8)*K + k0, (char*)Asm + seg*1024);
        }
        #pragma unroll
        for (int i = 0; i < 4; ++i) {
            int seg = w*4 + i;   // 0..15
            gload16(Bg + (size_t)(seg*8)*K + k0, (char*)Bsm + seg*1024);
        }
        __syncthreads();
        #pragma unroll
        for (int kk = 0; kk < 2; ++kk) {
            bf16x8 af[2], bfr[4];
            #pragma unroll
            for (int m = 0; m < 2; ++m) {
                int row = wr*32 + m*16 + (lane&15);
                af[m] = *(const bf16x8*)(Asm + row*64 + kk*32 + (lane>>4)*8);
            }
            #pragma unroll
            for (int n = 0; n < 4; ++n) {
                int col = wc*64 + n*16 + (lane&15);
                bfr[n] = *(const bf16x8*)(Bsm + col*64 + kk*32 + (lane>>4)*8);
            }
            #pragma unroll
            for (int m = 0; m < 2; ++m)
                #pragma unroll
                for (int n = 0; n < 4; ++n)
                    acc[m][n] = __builtin_amdgcn_mfma_f32_16x16x32_bf16(af[m], bfr[n], acc[m][n], 0, 0, 0);
        }
        __syncthreads();
    }
    int r0 = (lane >> 4) * 4;
    int ccol = lane & 15;
    #pragma unroll
    for (int m = 0; m < 2; ++m) {
        #pragma unroll
        for (int rr = 0; rr < 4; ++rr) {
            int row = m0 + wr*32 + m*16 + r0 + rr;
            int bi = row >> 10;
            #pragma unroll
            for (int n = 0; n < 4; ++n) {
                int col = n0 + wc*64 + n*16 + ccol;
                float val = acc[m][n][rr] + bias[col];
                C[(size_t)row*N + col] += gate[(size_t)bi*4608 + col] * val;
            }
        }
    }
}

// ------- qkv split + RoPE: qkv (B,L,3456) bf16 -> q,k (B,NH,L,72); v TRANSPOSED (B,NH,72,L) -------
__global__ __launch_bounds__(256) void k_ropesplit(const __hip_bfloat16* __restrict__ qkv,
        const float* __restrict__ cosb, const float* __restrict__ sinb,
        __hip_bfloat16* __restrict__ q, __hip_bfloat16* __restrict__ k,
        __hip_bfloat16* __restrict__ v) {
    int idx = blockIdx.x*256 + threadIdx.x;   // B*NH*L*36
    if (idx >= 2*NHEAD*LTOK*36) return;
    int dp = idx % 36;
    int l  = (idx / 36) % LTOK;
    int h  = (idx / (36*LTOK)) % NHEAD;
    int b  = idx / (36*LTOK*NHEAD);
    int d0 = dp*2;
    size_t src = (size_t)(b*LTOK + l)*3456 + h*HDIM + d0;
    float qe = __bfloat162float(qkv[src]),        qo = __bfloat162float(qkv[src+1]);
    float ke = __bfloat162float(qkv[src+HIDN]),   ko = __bfloat162float(qkv[src+HIDN+1]);
    float ce = cosb[l*HDIM+d0], co = cosb[l*HDIM+d0+1];
    float se = sinb[l*HDIM+d0], so = sinb[l*HDIM+d0+1];
    size_t dst = (size_t)((b*NHEAD + h)*LTOK + l)*HDIM + d0;
    q[dst]   = __float2bfloat16(qe*ce - qo*se);
    q[dst+1] = __float2bfloat16(qo*co + qe*so);
    k[dst]   = __float2bfloat16(ke*ce - ko*se);
    k[dst+1] = __float2bfloat16(ko*co + ke*so);
    size_t vdst = ((size_t)(b*NHEAD + h)*HDIM + d0)*LTOK + l;
    v[vdst]        = qkv[src+2*HIDN];
    v[vdst+LTOK]   = qkv[src+2*HIDN+1];
}

// ------- MFMA flash attention: block = 64 q-rows of one head, 4 waves x 16 rows -------
__global__ __launch_bounds__(256) void k_attn_mfma(
        const __hip_bfloat16* __restrict__ q,
        const __hip_bfloat16* __restrict__ k,
        const __hip_bfloat16* __restrict__ vt,
        __hip_bfloat16* __restrict__ o) {
    int blk = blockIdx.x;          // B*NH*16 = 512
    int qt = blk & 15, h = (blk >> 4) & 15, b = blk >> 8;
    const float scale = 0.117851130f;   // 1/sqrt(72)
    __shared__ __hip_bfloat16 Ksm[64*104];   // [key][d] stride 104; d>=72 zero
    __shared__ __hip_bfloat16 Vsm[80*72];    // [d][key] stride 72; rows 72..79 zero
    __shared__ __hip_bfloat16 Psm[4][16*72]; // per-wave P
    int tid = threadIdx.x, lane = tid & 63, w = tid >> 6;
    int l15 = lane & 15, g = lane >> 4;
    const __hip_bfloat16* qg = q  + ((size_t)(b*NHEAD + h)*LTOK + qt*64)*HDIM;
    const __hip_bfloat16* kg = k  + (size_t)(b*NHEAD + h)*LTOK*HDIM;
    const __hip_bfloat16* vg = vt + (size_t)(b*NHEAD + h)*HDIM*LTOK;

    {
        bf16x8 z = {};
        *(bf16x8*)(Ksm + (tid>>2)*104 + 72 + (tid&3)*8) = z;
        if (tid < 72) *(bf16x8*)(Vsm + (72 + tid/9)*72 + (tid%9)*8) = z;
    }
    for (int i = tid; i < 576; i += 256) {
        int r = i/9, s = i%9;
        *(bf16x8*)(Ksm + r*104 + s*8) = *(const bf16x8*)(qg + r*HDIM + s*8);
    }
    __syncthreads();
    bf16x8 qf[3];
    #pragma unroll
    for (int c = 0; c < 3; ++c)
        qf[c] = *(const bf16x8*)(Ksm + (w*16 + l15)*104 + c*32 + g*8);
    __syncthreads();

    f32x4 oacc[5] = {};
    float mold[4] = {-1e30f, -1e30f, -1e30f, -1e30f};
    float lsum[4] = {};

    for (int kt = 0; kt < 16; ++kt) {
        for (int i = tid; i < 576; i += 256) {
            int r = i/9, s = i%9;
            *(bf16x8*)(Ksm + r*104 + s*8) = *(const bf16x8*)(kg + (size_t)(kt*64 + r)*HDIM + s*8);
        }
        for (int i = tid; i < 576; i += 256) {
            int r = i>>3, s = i&7;
            *(bf16x8*)(Vsm + r*72 + s*8) = *(const bf16x8*)(vg + (size_t)r*LTOK + kt*64 + s*8);
        }
        __syncthreads();
        f32x4 st[4] = {};
        #pragma unroll
        for (int t = 0; t < 4; ++t) {
            #pragma unroll
            for (int c = 0; c < 3; ++c) {
                bf16x8 kf = *(const bf16x8*)(Ksm + (t*16 + l15)*104 + c*32 + g*8);
                st[t] = __builtin_amdgcn_mfma_f32_16x16x32_bf16(qf[c], kf, st[t], 0, 0, 0);
            }
        }
        #pragma unroll
        for (int r = 0; r < 4; ++r) {
            float mt = fmaxf(fmaxf(st[0][r], st[1][r]), fmaxf(st[2][r], st[3][r]));
            mt = fmaxf(mt, __shfl_xor(mt, 1));
            mt = fmaxf(mt, __shfl_xor(mt, 2));
            mt = fmaxf(mt, __shfl_xor(mt, 4));
            mt = fmaxf(mt, __shfl_xor(mt, 8));
            float mn = fmaxf(mold[r], mt);
            float corr = __expf((mold[r] - mn) * scale);
            mold[r] = mn;
            lsum[r] *= corr;
            #pragma unroll
            for (int dt = 0; dt < 5; ++dt) oacc[dt][r] *= corr;
            float rs = 0.f;
            #pragma unroll
            for (int t = 0; t < 4; ++t) {
                float p = __expf((st[t][r] - mn) * scale);
                rs += p;
                Psm[w][(g*4 + r)*72 + t*16 + l15] = __float2bfloat16(p);
            }
            rs += __shfl_xor(rs, 1);
            rs += __shfl_xor(rs, 2);
            rs += __shfl_xor(rs, 4);
            rs += __shfl_xor(rs, 8);
            lsum[r] += rs;
        }
        bf16x8 pa[2];
        #pragma unroll
        for (int c = 0; c < 2; ++c)
            pa[c] = *(const bf16x8*)(&Psm[w][l15*72 + c*32 + g*8]);
        #pragma unroll
        for (int dt = 0; dt < 5; ++dt) {
            #pragma unroll
            for (int c = 0; c < 2; ++c) {
                bf16x8 vf = *(const bf16x8*)(Vsm + (dt*16 + l15)*72 + c*32 + g*8);
                oacc[dt] = __builtin_amdgcn_mfma_f32_16x16x32_bf16(pa[c], vf, oacc[dt], 0, 0, 0);
            }
        }
        __syncthreads();
    }
    #pragma unroll
    for (int r = 0; r < 4; ++r) {
        float inv = 1.f / lsum[r];
        int row = qt*64 + w*16 + g*4 + r;
        __hip_bfloat16* op = o + ((size_t)b*LTOK + row)*HIDN + h*HDIM;
        #pragma unroll
        for (int dt = 0; dt < 5; ++dt) {
            int d = dt*16 + l15;
            if (d < HDIM) op[d] = __float2bfloat16(oacc[dt][r] * inv);
        }
    }
}

// ---------------- gated linear unit: mh = silu(x1)*x2 (bf16 in/out) ----------------
__global__ __launch_bounds__(256) void k_glu(const __hip_bfloat16* __restrict__ x12,
        __hip_bfloat16* __restrict__ mh) {
    int idx = blockIdx.x*256 + threadIdx.x;   // 2048*3072
    int m = idx / MLPM, jj = idx % MLPM;
    float x1 = __bfloat162float(x12[(size_t)m*6144 + jj]);
    float x2 = __bfloat162float(x12[(size_t)m*6144 + MLPM + jj]);
    mh[idx] = __float2bfloat16(x1 / (1.f + __expf(-x1)) * x2);
}

// ---------------- final norm + linear + unpatchify ----------------
__global__ __launch_bounds__(256) void k_final(const float* __restrict__ hx,
        const float* __restrict__ fnw, const float* __restrict__ fmod,
        const float* __restrict__ flw, const float* __restrict__ flb,
        float* __restrict__ out) {
    int m = blockIdx.x; int b = m >> 10, l = m & 1023;
    int tid = threadIdx.x;
    const float* row = hx + (size_t)m*HIDN;
    float part = 0.f;
    for (int j = tid; j < HIDN; j += 256) { float v2 = row[j]; part += v2*v2; }
    for (int off = 32; off; off >>= 1) part += __shfl_xor(part, off);
    __shared__ float wsum[4];
    __shared__ float hfs[HIDN];
    __shared__ float red[4][16];
    if ((tid & 63) == 0) wsum[tid >> 6] = part;
    __syncthreads();
    float rs = rsqrtf((wsum[0]+wsum[1]+wsum[2]+wsum[3]) * (1.f/HIDN) + 1e-6f);
    const float* fm = fmod + (size_t)b*2304;
    for (int j = tid; j < HIDN; j += 256)
        hfs[j] = row[j] * rs * fnw[j] * (1.f + fm[HIDN + j]) + fm[j];
    __syncthreads();
    float pacc[16] = {};
    for (int j = tid; j < HIDN; j += 256) {
        float hv = hfs[j];
        #pragma unroll
        for (int kk = 0; kk < 16; ++kk) pacc[kk] += hv * flw[j*16 + kk];
    }
    #pragma unroll
    for (int kk = 0; kk < 16; ++kk)
        for (int off = 32; off; off >>= 1) pacc[kk] += __shfl_xor(pacc[kk], off);
    if ((tid & 63) == 0) {
        int w = tid >> 6;
        #pragma unroll
        for (int kk = 0; kk < 16; ++kk) red[w][kk] = pacc[kk];
    }
    __syncthreads();
    if (tid < 16) {
        float val = red[0][tid] + red[1][tid] + red[2][tid] + red[3][tid] + flb[tid];
        int pi = tid >> 3, pj = (tid >> 2) & 1, c = tid & 3;
        int si = l >> 5, sj = l & 31;
        out[((size_t)(b*4 + c)*64 + si*2 + pi)*64 + sj*2 + pj] = val;
    }
}

extern "C" void kernel_launch(void* const* d_in, const int* in_sizes, int n_in,
                              void* d_out, int out_size, void* d_ws, size_t ws_size,
                              hipStream_t stream) {
    const float* x        = (const float*)d_in[0];
    const float* t        = (const float*)d_in[1];
    const int*   y        = (const int*)  d_in[2];
    const float* patch_w  = (const float*)d_in[3];
    const float* patch_b  = (const float*)d_in[4];
    const float* t_w1     = (const float*)d_in[5];
    const float* t_b1     = (const float*)d_in[6];
    const float* t_w2     = (const float*)d_in[7];
    const float* t_b2     = (const float*)d_in[8];
    const float* y_table  = (const float*)d_in[9];
    const float* norm1_w  = (const float*)d_in[10];
    const float* qkv_w    = (const float*)d_in[11];
    const float* qkv_b    = (const float*)d_in[12];
    const float* out_w    = (const float*)d_in[13];
    const float* out_b    = (const float*)d_in[14];
    const float* norm2_w  = (const float*)d_in[15];
    const float* mlp_w12  = (const float*)d_in[16];
    const float* mlp_b12  = (const float*)d_in[17];
    const float* mlp_w3   = (const float*)d_in[18];
    const float* mlp_b3   = (const float*)d_in[19];
    const float* adaln_w  = (const float*)d_in[20];
    const float* adaln_b  = (const float*)d_in[21];
    const float* fnorm_w  = (const float*)d_in[22];
    const float* fadaln_w = (const float*)d_in[23];
    const float* fadaln_b = (const float*)d_in[24];
    const float* flin_w   = (const float*)d_in[25];
    const float* flin_b   = (const float*)d_in[26];

    char* base = (char*)d_ws;
    float*          hx    = (float*)(base);                       //  9,437,184 B
    __hip_bfloat16* qkvbf = (__hip_bfloat16*)(base +  9437184);   // 25,165,824 B (qkv & x12)
    __hip_bfloat16* qbf   = (__hip_bfloat16*)(base + 34603008);   //  4,718,592 B
    __hip_bfloat16* kbf   = (__hip_bfloat16*)(base + 39321600);   //  4,718,592 B
    __hip_bfloat16* vbf   = (__hip_bfloat16*)(base + 44040192);   //  4,718,592 B (B,NH,72,L)
    __hip_bfloat16* hbf   = (__hip_bfloat16*)(base + 48758784);   //  4,718,592 B
    __hip_bfloat16* mhbf  = qbf;                                  // aliases q/k/v (consumed)
    __hip_bfloat16* wtb   = (__hip_bfloat16*)(base + 53477376);   // 31,850,496 B
    float* temb1 = (float*)(base + 85327872);        // 9216 B
    float* csilu = (float*)(base + 85337088);        // 9216 B
    float* modb  = (float*)(base + 85346304);        // 147456 B [4][2][4608]
    float* fmod  = (float*)(base + 85493760);        // 18432 B  [2][2304]
    float* cosb  = (float*)(base + 85512192);        // 294912 B
    float* sinb  = (float*)(base + 85807104);        // 294912 B
    float* condp = (float*)(base + 86102016);        // 663552 B [4][2][20736]
    float* csilup= (float*)(base + 86765568);        // 36864 B  [4][2][1152]
    // total 86,802,432 B = 86.8 MB

    __hip_bfloat16* wt_qkv = wtb;                        // [3456][1152]
    __hip_bfloat16* wt_out = wt_qkv + 3456*1152;         // [1152][1152]
    __hip_bfloat16* wt_m12 = wt_out + 1152*1152;         // [6144][1152]
    __hip_bfloat16* wt_m3  = wt_m12 + 6144*1152;         // [1152][3072]

    k_patch<<<2048, 256, 0, stream>>>(x, patch_w, patch_b, hx);
    k_temb1_v2<<<dim3(9,2), 256, 0, stream>>>(t, t_w1, t_b1, temb1);
    k_csilu_s1<<<dim3(9,4), 256, 0, stream>>>(temb1, t_w2, csilup);
    k_csilu_s2<<<dim3(9,2), 128, 0, stream>>>(csilup, t_b2, y_table, y, csilu);
    k_cond_s1<<<dim3(162,4), 256, 0, stream>>>(csilu, adaln_w, fadaln_w, condp);
    k_cond_s2<<<dim3(81,2), 256, 0, stream>>>(condp, adaln_b, fadaln_b, modb, fmod);
    k_rope<<<288, 256, 0, stream>>>(cosb, sinb);

    for (int d = 0; d < 4; ++d) {
        const float* modd = modb + (size_t)d*2*4608;
        k_castT<<<dim3(108,36), dim3(32,8), 0, stream>>>(qkv_w  + (size_t)d*HIDN*3456, wt_qkv, HIDN, 3456);
        k_castT<<<dim3( 36,36), dim3(32,8), 0, stream>>>(out_w  + (size_t)d*HIDN*HIDN, wt_out, HIDN, HIDN);
        k_castT<<<dim3(192,36), dim3(32,8), 0, stream>>>(mlp_w12+ (size_t)d*HIDN*6144, wt_m12, HIDN, 6144);
        k_castT<<<dim3( 36,96), dim3(32,8), 0, stream>>>(mlp_w3 + (size_t)d*MLPM*HIDN, wt_m3,  MLPM, HIDN);

        k_rms<<<2048, 256, 0, stream>>>(hx, norm1_w + d*HIDN, modd + 0*HIDN, hbf);
        k_gemm_bf16<0, __hip_bfloat16><<<dim3(27,16), 256, 0, stream>>>(hbf, wt_qkv,
                qkv_b + d*3456, qkvbf, MTOK, 3456, HIDN, nullptr);
        k_ropesplit<<<4608, 256, 0, stream>>>(qkvbf, cosb, sinb, qbf, kbf, vbf);
        k_attn_mfma<<<512, 256, 0, stream>>>(qbf, kbf, vbf, hbf);
        k_gemm64<<<dim3(9,32), 256, 0, stream>>>(hbf, wt_out,
                out_b + d*HIDN, hx, MTOK, HIDN, HIDN, modd + 1*HIDN);
        k_rms<<<2048, 256, 0, stream>>>(hx, norm2_w + d*HIDN, modd + 2*HIDN, hbf);
        k_gemm_bf16<0, __hip_bfloat16><<<dim3(48,16), 256, 0, stream>>>(hbf, wt_m12,
                mlp_b12 + d*6144, qkvbf, MTOK, 6144, HIDN, nullptr);
        k_glu<<<24576, 256, 0, stream>>>(qkvbf, mhbf);
        k_gemm64<<<dim3(9,32), 256, 0, stream>>>(mhbf, wt_m3,
                mlp_b3 + d*HIDN, hx, MTOK, HIDN, MLPM, modd + 3*HIDN);
    }
    k_final<<<2048, 256, 0, stream>>>(hx, fnorm_w, fmod, flin_w, flin_b, (float*)d_out);
}

// Round 6
// 1171.169 us; speedup vs baseline: 5.3409x; 1.1362x over previous
//
#include <hip/hip_runtime.h>
#include <hip/hip_bf16.h>

#define HIDN 1152
#define NHEAD 16
#define HDIM 72
#define LTOK 1024
#define MTOK 2048
#define MLPM 3072

typedef short bf16x8 __attribute__((ext_vector_type(8)));
typedef float f32x4 __attribute__((ext_vector_type(4)));

__device__ __forceinline__ void gload16(const void* g, void* l) {
    __builtin_amdgcn_global_load_lds(
        (const __attribute__((address_space(1))) void*)g,
        (__attribute__((address_space(3))) void*)l,
        16, 0, 0);
}

// ---------------- patch embed: x (B,4,64,64) -> hx (2048,1152) ----------------
__global__ __launch_bounds__(256) void k_patch(const float* __restrict__ x,
        const float* __restrict__ pw, const float* __restrict__ pb,
        float* __restrict__ h) {
    int m = blockIdx.x;            // 0..2047
    int b = m >> 10, l = m & 1023;
    int si = l >> 5, sj = l & 31;
    __shared__ float toks[16];
    int tid = threadIdx.x;
    if (tid < 16) {
        int pi = tid >> 3, pj = (tid >> 2) & 1, c = tid & 3;
        toks[tid] = x[((size_t)(b*4 + c)*64 + si*2 + pi)*64 + sj*2 + pj];
    }
    __syncthreads();
    for (int o = tid; o < HIDN; o += 256) {
        float acc = pb[o];
        #pragma unroll
        for (int kk = 0; kk < 16; ++kk) acc += toks[kk] * pw[kk*HIDN + o];
        h[(size_t)m*HIDN + o] = acc;
    }
}

// ------- temb1 = silu(timestep_emb @ w1 + b1): grid (9,2), 2-way K-split in-block -------
__global__ __launch_bounds__(256) void k_temb1_v2(const float* __restrict__ t,
        const float* __restrict__ w1, const float* __restrict__ b1,
        float* __restrict__ temb1) {
    int jt = blockIdx.x, b = blockIdx.y;
    int tid = threadIdx.x;
    __shared__ float emb[256];
    __shared__ float red[128];
    float tv = t[b];
    if (tid < 128) { float f = __expf(-logf(10000.f) * (float)tid / 128.f);        emb[tid] = cosf(tv * f); }
    else           { float f = __expf(-logf(10000.f) * (float)(tid - 128) / 128.f); emb[tid] = sinf(tv * f); }
    __syncthreads();
    int o = jt*128 + (tid & 127), s = tid >> 7;
    float acc = 0.f;
    for (int k = s*128; k < s*128 + 128; ++k) acc += emb[k] * w1[(size_t)k*HIDN + o];
    if (s) red[tid & 127] = acc;
    __syncthreads();
    if (!s) {
        float v = acc + red[tid] + b1[o];
        temb1[b*HIDN + o] = v / (1.f + __expf(-v));
    }
}

// ------- csilu stage 1: partial[kz][b][o] = temb1[b] @ w2[kz-slice]: grid (9,4) -------
__global__ __launch_bounds__(256) void k_csilu_s1(const float* __restrict__ temb1,
        const float* __restrict__ w2, float* __restrict__ csilup) {
    int jt = blockIdx.x, kz = blockIdx.y;
    int tid = threadIdx.x;
    __shared__ float t1s[2][288];
    __shared__ float red[2][128];
    for (int i = tid; i < 576; i += 256)
        t1s[i/288][i%288] = temb1[(i/288)*HIDN + kz*288 + (i%288)];
    __syncthreads();
    int o = jt*128 + (tid & 127), s = tid >> 7;
    float a0 = 0.f, a1 = 0.f;
    for (int i = s*144; i < s*144 + 144; ++i) {
        float wv = w2[(size_t)(kz*288 + i)*HIDN + o];
        a0 += t1s[0][i]*wv; a1 += t1s[1][i]*wv;
    }
    if (s) { red[0][tid & 127] = a0; red[1][tid & 127] = a1; }
    __syncthreads();
    if (!s) {
        csilup[(kz*2 + 0)*HIDN + o] = a0 + red[0][tid];
        csilup[(kz*2 + 1)*HIDN + o] = a1 + red[1][tid];
    }
}

// ------- csilu stage 2: reduce + b2 + y_table[y] + silu: grid (9,2) x 128 -------
__global__ __launch_bounds__(128) void k_csilu_s2(const float* __restrict__ csilup,
        const float* __restrict__ b2, const float* __restrict__ ytab,
        const int* __restrict__ y, float* __restrict__ csilu) {
    int o = blockIdx.x*128 + threadIdx.x;
    int b = blockIdx.y;
    float acc = b2[o] + ytab[(size_t)y[b]*HIDN + o];
    #pragma unroll
    for (int kz = 0; kz < 4; ++kz) acc += csilup[(kz*2 + b)*HIDN + o];
    csilu[b*HIDN + o] = acc / (1.f + __expf(-acc));
}

// ------- conditioning stage 1: all adaln (4 layers x 4608) + fadaln (2304) cols -------
__global__ __launch_bounds__(256) void k_cond_s1(const float* __restrict__ csilu,
        const float* __restrict__ adaln_w, const float* __restrict__ fadaln_w,
        float* __restrict__ condp) {
    int ct = blockIdx.x, kz = blockIdx.y;
    int tid = threadIdx.x;
    int c0 = ct*128;
    const float* Wb; int rstride;
    if (c0 < 18432) { int d = c0/4608; Wb = adaln_w + (size_t)d*HIDN*4608 + (c0 % 4608); rstride = 4608; }
    else            { Wb = fadaln_w + (c0 - 18432); rstride = 2304; }
    __shared__ float cs[2][288];
    __shared__ float red[2][128];
    for (int i = tid; i < 576; i += 256)
        cs[i/288][i%288] = csilu[(i/288)*HIDN + kz*288 + (i%288)];
    __syncthreads();
    int o = tid & 127, s = tid >> 7;
    float a0 = 0.f, a1 = 0.f;
    for (int i = s*144; i < s*144 + 144; ++i) {
        float wv = Wb[(size_t)(kz*288 + i)*rstride + o];
        a0 += cs[0][i]*wv; a1 += cs[1][i]*wv;
    }
    if (s) { red[0][o] = a0; red[1][o] = a1; }
    __syncthreads();
    if (!s) {
        condp[((size_t)kz*2 + 0)*20736 + c0 + o] = a0 + red[0][o];
        condp[((size_t)kz*2 + 1)*20736 + c0 + o] = a1 + red[1][o];
    }
}

// ------- conditioning stage 2: reduce 4 partials + bias -> modb / fmod: grid (81,2) -------
__global__ __launch_bounds__(256) void k_cond_s2(const float* __restrict__ condp,
        const float* __restrict__ adaln_b, const float* __restrict__ fadaln_b,
        float* __restrict__ modb, float* __restrict__ fmod) {
    int c = blockIdx.x*256 + threadIdx.x;
    int b = blockIdx.y;
    float acc = 0.f;
    #pragma unroll
    for (int kz = 0; kz < 4; ++kz) acc += condp[((size_t)kz*2 + b)*20736 + c];
    if (c < 18432) {
        int d = c/4608, j = c%4608;
        modb[((size_t)d*2 + b)*4608 + j] = acc + adaln_b[(size_t)d*4608 + j];
    } else {
        int j = c - 18432;
        fmod[(size_t)b*2304 + j] = acc + fadaln_b[j];
    }
}

// ---------------- RoPE tables (1024, 72) ----------------
__global__ __launch_bounds__(256) void k_rope(float* __restrict__ cosb, float* __restrict__ sinb) {
    int idx = blockIdx.x*256 + threadIdx.x;
    if (idx >= LTOK*HDIM) return;
    int l = idx / HDIM, dd = idx % HDIM;
    int i = l >> 5, j = l & 31;
    int pos = (dd < 36) ? i : j;
    int mm = ((dd < 36) ? dd : dd - 36) >> 1;
    float f = __expf(-logf(10000.f) * (float)mm / 18.f);
    float fr = (float)pos * f;
    cosb[idx] = cosf(fr);
    sinb[idx] = sinf(fr);
}

// ---------------- rmsnorm * (1 + s_mod) -> bf16 ----------------
__global__ __launch_bounds__(256) void k_rms(const float* __restrict__ hx,
        const float* __restrict__ nw, const float* __restrict__ smod,
        __hip_bfloat16* __restrict__ outp) {
    int m = blockIdx.x; int b = m >> 10;
    int tid = threadIdx.x;
    const float* row = hx + (size_t)m*HIDN;
    float part = 0.f;
    for (int j = tid; j < HIDN; j += 256) { float v = row[j]; part += v*v; }
    for (int off = 32; off; off >>= 1) part += __shfl_xor(part, off);
    __shared__ float wsum[4];
    if ((tid & 63) == 0) wsum[tid >> 6] = part;
    __syncthreads();
    float rs = rsqrtf((wsum[0]+wsum[1]+wsum[2]+wsum[3]) * (1.f/HIDN) + 1e-6f);
    const float* sb = smod + (size_t)b*4608;
    __hip_bfloat16* orow = outp + (size_t)m*HIDN;
    for (int j = tid; j < HIDN; j += 256)
        orow[j] = __float2bfloat16(row[j] * rs * nw[j] * (1.f + sb[j]));
}

// ---------------- weight cast+transpose: W [K][N] fp32 -> Wt [N][K] bf16 ----------------
__global__ __launch_bounds__(256) void k_castT(const float* __restrict__ W,
        __hip_bfloat16* __restrict__ Wt, int K, int N) {
    __shared__ float tile[32][33];
    int n0 = blockIdx.x*32, k0 = blockIdx.y*32;
    int tx = threadIdx.x, ty = threadIdx.y;   // 32, 8
    for (int i = ty; i < 32; i += 8)
        tile[i][tx] = W[(size_t)(k0+i)*N + n0 + tx];
    __syncthreads();
    for (int i = ty; i < 32; i += 8)
        Wt[(size_t)(n0+i)*K + k0 + tx] = __float2bfloat16(tile[tx][i]);
}

// ---------------- bf16 MFMA GEMM 128x128: A [M][K], Wt [N][K] ------
// LDS tiles stay LINEAR (global_load_lds requirement); bank-conflict fix is the
// both-sides XOR swizzle (rule #21): global source k-slot ^= row&7 at staging,
// fragment ds_read slot = (kk*4+g) ^ (lane&7). Bit-identical math, conflict-free reads.
// EPI 0: C = bf16(A@W^T + bias)    EPI 1: C(f32) += gate[b]*(A@W^T + bias)
template<int EPI, typename OutT>
__global__ __launch_bounds__(256) void k_gemm_bf16(
        const __hip_bfloat16* __restrict__ A,
        const __hip_bfloat16* __restrict__ Wt,
        const float* __restrict__ bias,
        OutT* __restrict__ C, int M, int N, int K,
        const float* __restrict__ gate) {
    __shared__ __hip_bfloat16 Asm[128*64];
    __shared__ __hip_bfloat16 Bsm[128*64];
    int tid = threadIdx.x;
    int lane = tid & 63, w = tid >> 6;
    int wr = w >> 1, wc = w & 1;
    int m0 = blockIdx.y * 128, n0 = blockIdx.x * 128;
    f32x4 acc[4][4] = {};
    int lr = lane >> 3, ls = lane & 7;
    int swz = ls ^ (lr & 7);              // pre-swizzled global k-slot
    int x7 = lane & 7;                    // row&7 of this lane's fragment rows
    const __hip_bfloat16* Ag = A  + (size_t)(m0 + lr)*K + swz*8;
    const __hip_bfloat16* Bg = Wt + (size_t)(n0 + lr)*K + swz*8;
    for (int k0 = 0; k0 < K; k0 += 64) {
        #pragma unroll
        for (int i = 0; i < 4; ++i) {
            int seg = w*4 + i;   // 0..15; 8 rows each
            gload16(Ag + (size_t)(seg*8)*K + k0, (char*)Asm + seg*1024);
            gload16(Bg + (size_t)(seg*8)*K + k0, (char*)Bsm + seg*1024);
        }
        __syncthreads();
        #pragma unroll
        for (int kk = 0; kk < 2; ++kk) {
            bf16x8 af[4], bfr[4];
            #pragma unroll
            for (int m = 0; m < 4; ++m) {
                int row = wr*64 + m*16 + (lane&15);
                af[m] = *(const bf16x8*)(Asm + row*64 + (((kk*4 + (lane>>4)) ^ x7) * 8));
            }
            #pragma unroll
            for (int n = 0; n < 4; ++n) {
                int col = wc*64 + n*16 + (lane&15);
                bfr[n] = *(const bf16x8*)(Bsm + col*64 + (((kk*4 + (lane>>4)) ^ x7) * 8));
            }
            #pragma unroll
            for (int m = 0; m < 4; ++m)
                #pragma unroll
                for (int n = 0; n < 4; ++n)
                    acc[m][n] = __builtin_amdgcn_mfma_f32_16x16x32_bf16(af[m], bfr[n], acc[m][n], 0, 0, 0);
        }
        __syncthreads();
    }
    int r0 = (lane >> 4) * 4;
    int ccol = lane & 15;
    #pragma unroll
    for (int m = 0; m < 4; ++m) {
        #pragma unroll
        for (int rr = 0; rr < 4; ++rr) {
            int row = m0 + wr*64 + m*16 + r0 + rr;
            int bi = row >> 10;
            #pragma unroll
            for (int n = 0; n < 4; ++n) {
                int col = n0 + wc*64 + n*16 + ccol;
                float val = acc[m][n][rr] + bias[col];
                if (EPI == 0) {
                    C[(size_t)row*N + col] = (OutT)__float2bfloat16(val);
                } else {
                    ((float*)C)[(size_t)row*N + col] += gate[(size_t)bi*4608 + col] * val;
                }
            }
        }
    }
}

// ------- bf16 MFMA GEMM 64x128 tile (higher occupancy for N=1152), EPI1 only -------
__global__ __launch_bounds__(256) void k_gemm64(
        const __hip_bfloat16* __restrict__ A,
        const __hip_bfloat16* __restrict__ Wt,
        const float* __restrict__ bias,
        float* __restrict__ C, int M, int N, int K,
        const float* __restrict__ gate) {
    __shared__ __hip_bfloat16 Asm[64*64];
    __shared__ __hip_bfloat16 Bsm[128*64];
    int tid = threadIdx.x;
    int lane = tid & 63, w = tid >> 6;
    int wr = w >> 1, wc = w & 1;
    int m0 = blockIdx.y * 64, n0 = blockIdx.x * 128;
    f32x4 acc[2][4] = {};
    int lr = lane >> 3, ls = lane & 7;
    int swz = ls ^ (lr & 7);
    int x7 = lane & 7;
    const __hip_bfloat16* Ag = A  + (size_t)(m0 + lr)*K + swz*8;
    const __hip_bfloat16* Bg = Wt + (size_t)(n0 + lr)*K + swz*8;
    for (int k0 = 0; k0 < K; k0 += 64) {
        #pragma unroll
        for (int i = 0; i < 2; ++i) {
            int seg = w*2 + i;   // 0..7
            gload16(Ag + (size_t)(seg*8)*K + k0, (char*)Asm + seg*1024);
        }
        #pragma unroll
        for (int i = 0; i < 4; ++i) {
            int seg = w*4 + i;   // 0..15
            gload16(Bg + (size_t)(seg*8)*K + k0, (char*)Bsm + seg*1024);
        }
        __syncthreads();
        #pragma unroll
        for (int kk = 0; kk < 2; ++kk) {
            bf16x8 af[2], bfr[4];
            #pragma unroll
            for (int m = 0; m < 2; ++m) {
                int row = wr*32 + m*16 + (lane&15);
                af[m] = *(const bf16x8*)(Asm + row*64 + (((kk*4 + (lane>>4)) ^ x7) * 8));
            }
            #pragma unroll
            for (int n = 0; n < 4; ++n) {
                int col = wc*64 + n*16 + (lane&15);
                bfr[n] = *(const bf16x8*)(Bsm + col*64 + (((kk*4 + (lane>>4)) ^ x7) * 8));
            }
            #pragma unroll
            for (int m = 0; m < 2; ++m)
                #pragma unroll
                for (int n = 0; n < 4; ++n)
                    acc[m][n] = __builtin_amdgcn_mfma_f32_16x16x32_bf16(af[m], bfr[n], acc[m][n], 0, 0, 0);
        }
        __syncthreads();
    }
    int r0 = (lane >> 4) * 4;
    int ccol = lane & 15;
    #pragma unroll
    for (int m = 0; m < 2; ++m) {
        #pragma unroll
        for (int rr = 0; rr < 4; ++rr) {
            int row = m0 + wr*32 + m*16 + r0 + rr;
            int bi = row >> 10;
            #pragma unroll
            for (int n = 0; n < 4; ++n) {
                int col = n0 + wc*64 + n*16 + ccol;
                float val = acc[m][n][rr] + bias[col];
                C[(size_t)row*N + col] += gate[(size_t)bi*4608 + col] * val;
            }
        }
    }
}

// ------- qkv split + RoPE: qkv (B,L,3456) bf16 -> q,k (B,NH,L,72); v TRANSPOSED (B,NH,72,L) -------
__global__ __launch_bounds__(256) void k_ropesplit(const __hip_bfloat16* __restrict__ qkv,
        const float* __restrict__ cosb, const float* __restrict__ sinb,
        __hip_bfloat16* __restrict__ q, __hip_bfloat16* __restrict__ k,
        __hip_bfloat16* __restrict__ v) {
    int idx = blockIdx.x*256 + threadIdx.x;   // B*NH*L*36
    if (idx >= 2*NHEAD*LTOK*36) return;
    int dp = idx % 36;
    int l  = (idx / 36) % LTOK;
    int h  = (idx / (36*LTOK)) % NHEAD;
    int b  = idx / (36*LTOK*NHEAD);
    int d0 = dp*2;
    size_t src = (size_t)(b*LTOK + l)*3456 + h*HDIM + d0;
    float qe = __bfloat162float(qkv[src]),        qo = __bfloat162float(qkv[src+1]);
    float ke = __bfloat162float(qkv[src+HIDN]),   ko = __bfloat162float(qkv[src+HIDN+1]);
    float ce = cosb[l*HDIM+d0], co = cosb[l*HDIM+d0+1];
    float se = sinb[l*HDIM+d0], so = sinb[l*HDIM+d0+1];
    size_t dst = (size_t)((b*NHEAD + h)*LTOK + l)*HDIM + d0;
    q[dst]   = __float2bfloat16(qe*ce - qo*se);
    q[dst+1] = __float2bfloat16(qo*co + qe*so);
    k[dst]   = __float2bfloat16(ke*ce - ko*se);
    k[dst+1] = __float2bfloat16(ko*co + ke*so);
    size_t vdst = ((size_t)(b*NHEAD + h)*HDIM + d0)*LTOK + l;
    v[vdst]        = qkv[src+2*HIDN];
    v[vdst+LTOK]   = qkv[src+2*HIDN+1];
}

// ------- MFMA flash attention: block = 64 q-rows of one head, 4 waves x 16 rows -------
__global__ __launch_bounds__(256) void k_attn_mfma(
        const __hip_bfloat16* __restrict__ q,
        const __hip_bfloat16* __restrict__ k,
        const __hip_bfloat16* __restrict__ vt,
        __hip_bfloat16* __restrict__ o) {
    int blk = blockIdx.x;          // B*NH*16 = 512
    int qt = blk & 15, h = (blk >> 4) & 15, b = blk >> 8;
    const float scale = 0.117851130f;   // 1/sqrt(72)
    __shared__ __hip_bfloat16 Ksm[64*104];   // [key][d] stride 104; d>=72 zero
    __shared__ __hip_bfloat16 Vsm[80*72];    // [d][key] stride 72; rows 72..79 zero
    __shared__ __hip_bfloat16 Psm[4][16*72]; // per-wave P
    int tid = threadIdx.x, lane = tid & 63, w = tid >> 6;
    int l15 = lane & 15, g = lane >> 4;
    const __hip_bfloat16* qg = q  + ((size_t)(b*NHEAD + h)*LTOK + qt*64)*HDIM;
    const __hip_bfloat16* kg = k  + (size_t)(b*NHEAD + h)*LTOK*HDIM;
    const __hip_bfloat16* vg = vt + (size_t)(b*NHEAD + h)*HDIM*LTOK;

    {
        bf16x8 z = {};
        *(bf16x8*)(Ksm + (tid>>2)*104 + 72 + (tid&3)*8) = z;
        if (tid < 72) *(bf16x8*)(Vsm + (72 + tid/9)*72 + (tid%9)*8) = z;
    }
    for (int i = tid; i < 576; i += 256) {
        int r = i/9, s = i%9;
        *(bf16x8*)(Ksm + r*104 + s*8) = *(const bf16x8*)(qg + r*HDIM + s*8);
    }
    __syncthreads();
    bf16x8 qf[3];
    #pragma unroll
    for (int c = 0; c < 3; ++c)
        qf[c] = *(const bf16x8*)(Ksm + (w*16 + l15)*104 + c*32 + g*8);
    __syncthreads();

    f32x4 oacc[5] = {};
    float mold[4] = {-1e30f, -1e30f, -1e30f, -1e30f};
    float lsum[4] = {};

    for (int kt = 0; kt < 16; ++kt) {
        for (int i = tid; i < 576; i += 256) {
            int r = i/9, s = i%9;
            *(bf16x8*)(Ksm + r*104 + s*8) = *(const bf16x8*)(kg + (size_t)(kt*64 + r)*HDIM + s*8);
        }
        for (int i = tid; i < 576; i += 256) {
            int r = i>>3, s = i&7;
            *(bf16x8*)(Vsm + r*72 + s*8) = *(const bf16x8*)(vg + (size_t)r*LTOK + kt*64 + s*8);
        }
        __syncthreads();
        f32x4 st[4] = {};
        #pragma unroll
        for (int t = 0; t < 4; ++t) {
            #pragma unroll
            for (int c = 0; c < 3; ++c) {
                bf16x8 kf = *(const bf16x8*)(Ksm + (t*16 + l15)*104 + c*32 + g*8);
                st[t] = __builtin_amdgcn_mfma_f32_16x16x32_bf16(qf[c], kf, st[t], 0, 0, 0);
            }
        }
        #pragma unroll
        for (int r = 0; r < 4; ++r) {
            float mt = fmaxf(fmaxf(st[0][r], st[1][r]), fmaxf(st[2][r], st[3][r]));
            mt = fmaxf(mt, __shfl_xor(mt, 1));
            mt = fmaxf(mt, __shfl_xor(mt, 2));
            mt = fmaxf(mt, __shfl_xor(mt, 4));
            mt = fmaxf(mt, __shfl_xor(mt, 8));
            float mn = fmaxf(mold[r], mt);
            float corr = __expf((mold[r] - mn) * scale);
            mold[r] = mn;
            lsum[r] *= corr;
            #pragma unroll
            for (int dt = 0; dt < 5; ++dt) oacc[dt][r] *= corr;
            float rs = 0.f;
            #pragma unroll
            for (int t = 0; t < 4; ++t) {
                float p = __expf((st[t][r] - mn) * scale);
                rs += p;
                Psm[w][(g*4 + r)*72 + t*16 + l15] = __float2bfloat16(p);
            }
            rs += __shfl_xor(rs, 1);
            rs += __shfl_xor(rs, 2);
            rs += __shfl_xor(rs, 4);
            rs += __shfl_xor(rs, 8);
            lsum[r] += rs;
        }
        bf16x8 pa[2];
        #pragma unroll
        for (int c = 0; c < 2; ++c)
            pa[c] = *(const bf16x8*)(&Psm[w][l15*72 + c*32 + g*8]);
        #pragma unroll
        for (int dt = 0; dt < 5; ++dt) {
            #pragma unroll
            for (int c = 0; c < 2; ++c) {
                bf16x8 vf = *(const bf16x8*)(Vsm + (dt*16 + l15)*72 + c*32 + g*8);
                oacc[dt] = __builtin_amdgcn_mfma_f32_16x16x32_bf16(pa[c], vf, oacc[dt], 0, 0, 0);
            }
        }
        __syncthreads();
    }
    #pragma unroll
    for (int r = 0; r < 4; ++r) {
        float inv = 1.f / lsum[r];
        int row = qt*64 + w*16 + g*4 + r;
        __hip_bfloat16* op = o + ((size_t)b*LTOK + row)*HIDN + h*HDIM;
        #pragma unroll
        for (int dt = 0; dt < 5; ++dt) {
            int d = dt*16 + l15;
            if (d < HDIM) op[d] = __float2bfloat16(oacc[dt][r] * inv);
        }
    }
}

// ---------------- gated linear unit: mh = silu(x1)*x2, bf16x8 vectorized ----------------
__global__ __launch_bounds__(256) void k_glu(const __hip_bfloat16* __restrict__ x12,
        __hip_bfloat16* __restrict__ mh) {
    int idx = blockIdx.x*256 + threadIdx.x;   // 2048*384
    int m = idx / 384, jj = (idx % 384)*8;
    bf16x8 v1 = *(const bf16x8*)(x12 + (size_t)m*6144 + jj);
    bf16x8 v2 = *(const bf16x8*)(x12 + (size_t)m*6144 + MLPM + jj);
    bf16x8 ov;
    #pragma unroll
    for (int i = 0; i < 8; ++i) {
        short s1 = v1[i], s2 = v2[i];
        float x1 = __bfloat162float(*(__hip_bfloat16*)&s1);
        float x2 = __bfloat162float(*(__hip_bfloat16*)&s2);
        __hip_bfloat16 r = __float2bfloat16(x1 / (1.f + __expf(-x1)) * x2);
        ov[i] = *(short*)&r;
    }
    *(bf16x8*)(mh + (size_t)m*MLPM + jj) = ov;
}

// ---------------- final norm + linear + unpatchify ----------------
__global__ __launch_bounds__(256) void k_final(const float* __restrict__ hx,
        const float* __restrict__ fnw, const float* __restrict__ fmod,
        const float* __restrict__ flw, const float* __restrict__ flb,
        float* __restrict__ out) {
    int m = blockIdx.x; int b = m >> 10, l = m & 1023;
    int tid = threadIdx.x;
    const float* row = hx + (size_t)m*HIDN;
    float part = 0.f;
    for (int j = tid; j < HIDN; j += 256) { float v2 = row[j]; part += v2*v2; }
    for (int off = 32; off; off >>= 1) part += __shfl_xor(part, off);
    __shared__ float wsum[4];
    __shared__ float hfs[HIDN];
    __shared__ float red[4][16];
    if ((tid & 63) == 0) wsum[tid >> 6] = part;
    __syncthreads();
    float rs = rsqrtf((wsum[0]+wsum[1]+wsum[2]+wsum[3]) * (1.f/HIDN) + 1e-6f);
    const float* fm = fmod + (size_t)b*2304;
    for (int j = tid; j < HIDN; j += 256)
        hfs[j] = row[j] * rs * fnw[j] * (1.f + fm[HIDN + j]) + fm[j];
    __syncthreads();
    float pacc[16] = {};
    for (int j = tid; j < HIDN; j += 256) {
        float hv = hfs[j];
        #pragma unroll
        for (int kk = 0; kk < 16; ++kk) pacc[kk] += hv * flw[j*16 + kk];
    }
    #pragma unroll
    for (int kk = 0; kk < 16; ++kk)
        for (int off = 32; off; off >>= 1) pacc[kk] += __shfl_xor(pacc[kk], off);
    if ((tid & 63) == 0) {
        int w = tid >> 6;
        #pragma unroll
        for (int kk = 0; kk < 16; ++kk) red[w][kk] = pacc[kk];
    }
    __syncthreads();
    if (tid < 16) {
        float val = red[0][tid] + red[1][tid] + red[2][tid] + red[3][tid] + flb[tid];
        int pi = tid >> 3, pj = (tid >> 2) & 1, c = tid & 3;
        int si = l >> 5, sj = l & 31;
        out[((size_t)(b*4 + c)*64 + si*2 + pi)*64 + sj*2 + pj] = val;
    }
}

extern "C" void kernel_launch(void* const* d_in, const int* in_sizes, int n_in,
                              void* d_out, int out_size, void* d_ws, size_t ws_size,
                              hipStream_t stream) {
    const float* x        = (const float*)d_in[0];
    const float* t        = (const float*)d_in[1];
    const int*   y        = (const int*)  d_in[2];
    const float* patch_w  = (const float*)d_in[3];
    const float* patch_b  = (const float*)d_in[4];
    const float* t_w1     = (const float*)d_in[5];
    const float* t_b1     = (const float*)d_in[6];
    const float* t_w2     = (const float*)d_in[7];
    const float* t_b2     = (const float*)d_in[8];
    const float* y_table  = (const float*)d_in[9];
    const float* norm1_w  = (const float*)d_in[10];
    const float* qkv_w    = (const float*)d_in[11];
    const float* qkv_b    = (const float*)d_in[12];
    const float* out_w    = (const float*)d_in[13];
    const float* out_b    = (const float*)d_in[14];
    const float* norm2_w  = (const float*)d_in[15];
    const float* mlp_w12  = (const float*)d_in[16];
    const float* mlp_b12  = (const float*)d_in[17];
    const float* mlp_w3   = (const float*)d_in[18];
    const float* mlp_b3   = (const float*)d_in[19];
    const float* adaln_w  = (const float*)d_in[20];
    const float* adaln_b  = (const float*)d_in[21];
    const float* fnorm_w  = (const float*)d_in[22];
    const float* fadaln_w = (const float*)d_in[23];
    const float* fadaln_b = (const float*)d_in[24];
    const float* flin_w   = (const float*)d_in[25];
    const float* flin_b   = (const float*)d_in[26];

    char* base = (char*)d_ws;
    float*          hx    = (float*)(base);                       //  9,437,184 B
    __hip_bfloat16* qkvbf = (__hip_bfloat16*)(base +  9437184);   // 25,165,824 B (qkv & x12)
    __hip_bfloat16* qbf   = (__hip_bfloat16*)(base + 34603008);   //  4,718,592 B
    __hip_bfloat16* kbf   = (__hip_bfloat16*)(base + 39321600);   //  4,718,592 B
    __hip_bfloat16* vbf   = (__hip_bfloat16*)(base + 44040192);   //  4,718,592 B (B,NH,72,L)
    __hip_bfloat16* hbf   = (__hip_bfloat16*)(base + 48758784);   //  4,718,592 B
    __hip_bfloat16* mhbf  = qbf;                                  // aliases q/k/v (consumed)
    __hip_bfloat16* wtb   = (__hip_bfloat16*)(base + 53477376);   // 31,850,496 B
    float* temb1 = (float*)(base + 85327872);        // 9216 B
    float* csilu = (float*)(base + 85337088);        // 9216 B
    float* modb  = (float*)(base + 85346304);        // 147456 B [4][2][4608]
    float* fmod  = (float*)(base + 85493760);        // 18432 B  [2][2304]
    float* cosb  = (float*)(base + 85512192);        // 294912 B
    float* sinb  = (float*)(base + 85807104);        // 294912 B
    float* condp = (float*)(base + 86102016);        // 663552 B [4][2][20736]
    float* csilup= (float*)(base + 86765568);        // 36864 B  [4][2][1152]
    // total 86,802,432 B = 86.8 MB

    __hip_bfloat16* wt_qkv = wtb;                        // [3456][1152]
    __hip_bfloat16* wt_out = wt_qkv + 3456*1152;         // [1152][1152]
    __hip_bfloat16* wt_m12 = wt_out + 1152*1152;         // [6144][1152]
    __hip_bfloat16* wt_m3  = wt_m12 + 6144*1152;         // [1152][3072]

    k_patch<<<2048, 256, 0, stream>>>(x, patch_w, patch_b, hx);
    k_temb1_v2<<<dim3(9,2), 256, 0, stream>>>(t, t_w1, t_b1, temb1);
    k_csilu_s1<<<dim3(9,4), 256, 0, stream>>>(temb1, t_w2, csilup);
    k_csilu_s2<<<dim3(9,2), 128, 0, stream>>>(csilup, t_b2, y_table, y, csilu);
    k_cond_s1<<<dim3(162,4), 256, 0, stream>>>(csilu, adaln_w, fadaln_w, condp);
    k_cond_s2<<<dim3(81,2), 256, 0, stream>>>(condp, adaln_b, fadaln_b, modb, fmod);
    k_rope<<<288, 256, 0, stream>>>(cosb, sinb);

    for (int d = 0; d < 4; ++d) {
        const float* modd = modb + (size_t)d*2*4608;
        k_castT<<<dim3(108,36), dim3(32,8), 0, stream>>>(qkv_w  + (size_t)d*HIDN*3456, wt_qkv, HIDN, 3456);
        k_castT<<<dim3( 36,36), dim3(32,8), 0, stream>>>(out_w  + (size_t)d*HIDN*HIDN, wt_out, HIDN, HIDN);
        k_castT<<<dim3(192,36), dim3(32,8), 0, stream>>>(mlp_w12+ (size_t)d*HIDN*6144, wt_m12, HIDN, 6144);
        k_castT<<<dim3( 36,96), dim3(32,8), 0, stream>>>(mlp_w3 + (size_t)d*MLPM*HIDN, wt_m3,  MLPM, HIDN);

        k_rms<<<2048, 256, 0, stream>>>(hx, norm1_w + d*HIDN, modd + 0*HIDN, hbf);
        k_gemm_bf16<0, __hip_bfloat16><<<dim3(27,16), 256, 0, stream>>>(hbf, wt_qkv,
                qkv_b + d*3456, qkvbf, MTOK, 3456, HIDN, nullptr);
        k_ropesplit<<<4608, 256, 0, stream>>>(qkvbf, cosb, sinb, qbf, kbf, vbf);
        k_attn_mfma<<<512, 256, 0, stream>>>(qbf, kbf, vbf, hbf);
        k_gemm64<<<dim3(9,32), 256, 0, stream>>>(hbf, wt_out,
                out_b + d*HIDN, hx, MTOK, HIDN, HIDN, modd + 1*HIDN);
        k_rms<<<2048, 256, 0, stream>>>(hx, norm2_w + d*HIDN, modd + 2*HIDN, hbf);
        k_gemm_bf16<0, __hip_bfloat16><<<dim3(48,16), 256, 0, stream>>>(hbf, wt_m12,
                mlp_b12 + d*6144, qkvbf, MTOK, 6144, HIDN, nullptr);
        k_glu<<<3072, 256, 0, stream>>>(qkvbf, mhbf);
        k_gemm64<<<dim3(9,32), 256, 0, stream>>>(mhbf, wt_m3,
                mlp_b3 + d*HIDN, hx, MTOK, HIDN, MLPM, modd + 3*HIDN);
    }
    k_final<<<2048, 256, 0, stream>>>(hx, fnorm_w, fmod, flin_w, flin_b, (float*)d_out);
}

// Round 7
// 1097.376 us; speedup vs baseline: 5.7000x; 1.0672x over previous
//
#include <hip/hip_runtime.h>
#include <hip/hip_bf16.h>

#define HIDN 1152
#define NHEAD 16
#define HDIM 72
#define LTOK 1024
#define MTOK 2048
#define MLPM 3072

typedef short bf16x8 __attribute__((ext_vector_type(8)));
typedef float f32x4 __attribute__((ext_vector_type(4)));

__device__ __forceinline__ void gload16(const void* g, void* l) {
    __builtin_amdgcn_global_load_lds(
        (const __attribute__((address_space(1))) void*)g,
        (__attribute__((address_space(3))) void*)l,
        16, 0, 0);
}

// ---------------- patch embed: x (B,4,64,64) -> hx (2048,1152) ----------------
__global__ __launch_bounds__(256) void k_patch(const float* __restrict__ x,
        const float* __restrict__ pw, const float* __restrict__ pb,
        float* __restrict__ h) {
    int m = blockIdx.x;            // 0..2047
    int b = m >> 10, l = m & 1023;
    int si = l >> 5, sj = l & 31;
    __shared__ float toks[16];
    int tid = threadIdx.x;
    if (tid < 16) {
        int pi = tid >> 3, pj = (tid >> 2) & 1, c = tid & 3;
        toks[tid] = x[((size_t)(b*4 + c)*64 + si*2 + pi)*64 + sj*2 + pj];
    }
    __syncthreads();
    for (int o = tid; o < HIDN; o += 256) {
        float acc = pb[o];
        #pragma unroll
        for (int kk = 0; kk < 16; ++kk) acc += toks[kk] * pw[kk*HIDN + o];
        h[(size_t)m*HIDN + o] = acc;
    }
}

// ------- temb1 = silu(timestep_emb @ w1 + b1): grid (9,2), 2-way K-split in-block -------
__global__ __launch_bounds__(256) void k_temb1_v2(const float* __restrict__ t,
        const float* __restrict__ w1, const float* __restrict__ b1,
        float* __restrict__ temb1) {
    int jt = blockIdx.x, b = blockIdx.y;
    int tid = threadIdx.x;
    __shared__ float emb[256];
    __shared__ float red[128];
    float tv = t[b];
    if (tid < 128) { float f = __expf(-logf(10000.f) * (float)tid / 128.f);        emb[tid] = cosf(tv * f); }
    else           { float f = __expf(-logf(10000.f) * (float)(tid - 128) / 128.f); emb[tid] = sinf(tv * f); }
    __syncthreads();
    int o = jt*128 + (tid & 127), s = tid >> 7;
    float acc = 0.f;
    for (int k = s*128; k < s*128 + 128; ++k) acc += emb[k] * w1[(size_t)k*HIDN + o];
    if (s) red[tid & 127] = acc;
    __syncthreads();
    if (!s) {
        float v = acc + red[tid] + b1[o];
        temb1[b*HIDN + o] = v / (1.f + __expf(-v));
    }
}

// ------- csilu stage 1: partial[kz][b][o] = temb1[b] @ w2[kz-slice]: grid (9,4) -------
__global__ __launch_bounds__(256) void k_csilu_s1(const float* __restrict__ temb1,
        const float* __restrict__ w2, float* __restrict__ csilup) {
    int jt = blockIdx.x, kz = blockIdx.y;
    int tid = threadIdx.x;
    __shared__ float t1s[2][288];
    __shared__ float red[2][128];
    for (int i = tid; i < 576; i += 256)
        t1s[i/288][i%288] = temb1[(i/288)*HIDN + kz*288 + (i%288)];
    __syncthreads();
    int o = jt*128 + (tid & 127), s = tid >> 7;
    float a0 = 0.f, a1 = 0.f;
    for (int i = s*144; i < s*144 + 144; ++i) {
        float wv = w2[(size_t)(kz*288 + i)*HIDN + o];
        a0 += t1s[0][i]*wv; a1 += t1s[1][i]*wv;
    }
    if (s) { red[0][tid & 127] = a0; red[1][tid & 127] = a1; }
    __syncthreads();
    if (!s) {
        csilup[(kz*2 + 0)*HIDN + o] = a0 + red[0][tid];
        csilup[(kz*2 + 1)*HIDN + o] = a1 + red[1][tid];
    }
}

// ------- csilu stage 2: reduce + b2 + y_table[y] + silu: grid (9,2) x 128 -------
__global__ __launch_bounds__(128) void k_csilu_s2(const float* __restrict__ csilup,
        const float* __restrict__ b2, const float* __restrict__ ytab,
        const int* __restrict__ y, float* __restrict__ csilu) {
    int o = blockIdx.x*128 + threadIdx.x;
    int b = blockIdx.y;
    float acc = b2[o] + ytab[(size_t)y[b]*HIDN + o];
    #pragma unroll
    for (int kz = 0; kz < 4; ++kz) acc += csilup[(kz*2 + b)*HIDN + o];
    csilu[b*HIDN + o] = acc / (1.f + __expf(-acc));
}

// ------- conditioning stage 1: all adaln (4 layers x 4608) + fadaln (2304) cols -------
__global__ __launch_bounds__(256) void k_cond_s1(const float* __restrict__ csilu,
        const float* __restrict__ adaln_w, const float* __restrict__ fadaln_w,
        float* __restrict__ condp) {
    int ct = blockIdx.x, kz = blockIdx.y;
    int tid = threadIdx.x;
    int c0 = ct*128;
    const float* Wb; int rstride;
    if (c0 < 18432) { int d = c0/4608; Wb = adaln_w + (size_t)d*HIDN*4608 + (c0 % 4608); rstride = 4608; }
    else            { Wb = fadaln_w + (c0 - 18432); rstride = 2304; }
    __shared__ float cs[2][288];
    __shared__ float red[2][128];
    for (int i = tid; i < 576; i += 256)
        cs[i/288][i%288] = csilu[(i/288)*HIDN + kz*288 + (i%288)];
    __syncthreads();
    int o = tid & 127, s = tid >> 7;
    float a0 = 0.f, a1 = 0.f;
    for (int i = s*144; i < s*144 + 144; ++i) {
        float wv = Wb[(size_t)(kz*288 + i)*rstride + o];
        a0 += cs[0][i]*wv; a1 += cs[1][i]*wv;
    }
    if (s) { red[0][o] = a0; red[1][o] = a1; }
    __syncthreads();
    if (!s) {
        condp[((size_t)kz*2 + 0)*20736 + c0 + o] = a0 + red[0][o];
        condp[((size_t)kz*2 + 1)*20736 + c0 + o] = a1 + red[1][o];
    }
}

// ------- conditioning stage 2: reduce 4 partials + bias -> modb / fmod: grid (81,2) -------
__global__ __launch_bounds__(256) void k_cond_s2(const float* __restrict__ condp,
        const float* __restrict__ adaln_b, const float* __restrict__ fadaln_b,
        float* __restrict__ modb, float* __restrict__ fmod) {
    int c = blockIdx.x*256 + threadIdx.x;
    int b = blockIdx.y;
    float acc = 0.f;
    #pragma unroll
    for (int kz = 0; kz < 4; ++kz) acc += condp[((size_t)kz*2 + b)*20736 + c];
    if (c < 18432) {
        int d = c/4608, j = c%4608;
        modb[((size_t)d*2 + b)*4608 + j] = acc + adaln_b[(size_t)d*4608 + j];
    } else {
        int j = c - 18432;
        fmod[(size_t)b*2304 + j] = acc + fadaln_b[j];
    }
}

// ---------------- RoPE tables (1024, 72) ----------------
__global__ __launch_bounds__(256) void k_rope(float* __restrict__ cosb, float* __restrict__ sinb) {
    int idx = blockIdx.x*256 + threadIdx.x;
    if (idx >= LTOK*HDIM) return;
    int l = idx / HDIM, dd = idx % HDIM;
    int i = l >> 5, j = l & 31;
    int pos = (dd < 36) ? i : j;
    int mm = ((dd < 36) ? dd : dd - 36) >> 1;
    float f = __expf(-logf(10000.f) * (float)mm / 18.f);
    float fr = (float)pos * f;
    cosb[idx] = cosf(fr);
    sinb[idx] = sinf(fr);
}

// ---------------- rmsnorm * (1 + s_mod) -> bf16 ----------------
__global__ __launch_bounds__(256) void k_rms(const float* __restrict__ hx,
        const float* __restrict__ nw, const float* __restrict__ smod,
        __hip_bfloat16* __restrict__ outp) {
    int m = blockIdx.x; int b = m >> 10;
    int tid = threadIdx.x;
    const float* row = hx + (size_t)m*HIDN;
    float part = 0.f;
    for (int j = tid; j < HIDN; j += 256) { float v = row[j]; part += v*v; }
    for (int off = 32; off; off >>= 1) part += __shfl_xor(part, off);
    __shared__ float wsum[4];
    if ((tid & 63) == 0) wsum[tid >> 6] = part;
    __syncthreads();
    float rs = rsqrtf((wsum[0]+wsum[1]+wsum[2]+wsum[3]) * (1.f/HIDN) + 1e-6f);
    const float* sb = smod + (size_t)b*4608;
    __hip_bfloat16* orow = outp + (size_t)m*HIDN;
    for (int j = tid; j < HIDN; j += 256)
        orow[j] = __float2bfloat16(row[j] * rs * nw[j] * (1.f + sb[j]));
}

// ---------------- weight cast+transpose: W [K][N] fp32 -> Wt [N][K] bf16 ----------------
__global__ __launch_bounds__(256) void k_castT(const float* __restrict__ W,
        __hip_bfloat16* __restrict__ Wt, int K, int N) {
    __shared__ float tile[32][33];
    int n0 = blockIdx.x*32, k0 = blockIdx.y*32;
    int tx = threadIdx.x, ty = threadIdx.y;   // 32, 8
    for (int i = ty; i < 32; i += 8)
        tile[i][tx] = W[(size_t)(k0+i)*N + n0 + tx];
    __syncthreads();
    for (int i = ty; i < 32; i += 8)
        Wt[(size_t)(n0+i)*K + k0 + tx] = __float2bfloat16(tile[tx][i]);
}

// ---------------- bf16 MFMA GEMM 128x128: A [M][K], Wt [N][K] ------
// Both-sides XOR swizzle (rule #21): global k-slot ^= row&7 at staging,
// fragment slot = (kk*4+g) ^ (lane&7). Bit-identical math, conflict-free reads.
// EPI 0: C = bf16(A@W^T + bias)    EPI 1: C(f32) += gate[b]*(A@W^T + bias)
template<int EPI, typename OutT>
__global__ __launch_bounds__(256) void k_gemm_bf16(
        const __hip_bfloat16* __restrict__ A,
        const __hip_bfloat16* __restrict__ Wt,
        const float* __restrict__ bias,
        OutT* __restrict__ C, int M, int N, int K,
        const float* __restrict__ gate) {
    __shared__ __hip_bfloat16 Asm[128*64];
    __shared__ __hip_bfloat16 Bsm[128*64];
    int tid = threadIdx.x;
    int lane = tid & 63, w = tid >> 6;
    int wr = w >> 1, wc = w & 1;
    int m0 = blockIdx.y * 128, n0 = blockIdx.x * 128;
    f32x4 acc[4][4] = {};
    int lr = lane >> 3, ls = lane & 7;
    int swz = ls ^ (lr & 7);              // pre-swizzled global k-slot
    int x7 = lane & 7;
    const __hip_bfloat16* Ag = A  + (size_t)(m0 + lr)*K + swz*8;
    const __hip_bfloat16* Bg = Wt + (size_t)(n0 + lr)*K + swz*8;
    for (int k0 = 0; k0 < K; k0 += 64) {
        #pragma unroll
        for (int i = 0; i < 4; ++i) {
            int seg = w*4 + i;
            gload16(Ag + (size_t)(seg*8)*K + k0, (char*)Asm + seg*1024);
            gload16(Bg + (size_t)(seg*8)*K + k0, (char*)Bsm + seg*1024);
        }
        __syncthreads();
        #pragma unroll
        for (int kk = 0; kk < 2; ++kk) {
            bf16x8 af[4], bfr[4];
            #pragma unroll
            for (int m = 0; m < 4; ++m) {
                int row = wr*64 + m*16 + (lane&15);
                af[m] = *(const bf16x8*)(Asm + row*64 + (((kk*4 + (lane>>4)) ^ x7) * 8));
            }
            #pragma unroll
            for (int n = 0; n < 4; ++n) {
                int col = wc*64 + n*16 + (lane&15);
                bfr[n] = *(const bf16x8*)(Bsm + col*64 + (((kk*4 + (lane>>4)) ^ x7) * 8));
            }
            #pragma unroll
            for (int m = 0; m < 4; ++m)
                #pragma unroll
                for (int n = 0; n < 4; ++n)
                    acc[m][n] = __builtin_amdgcn_mfma_f32_16x16x32_bf16(af[m], bfr[n], acc[m][n], 0, 0, 0);
        }
        __syncthreads();
    }
    int r0 = (lane >> 4) * 4;
    int ccol = lane & 15;
    #pragma unroll
    for (int m = 0; m < 4; ++m) {
        #pragma unroll
        for (int rr = 0; rr < 4; ++rr) {
            int row = m0 + wr*64 + m*16 + r0 + rr;
            int bi = row >> 10;
            #pragma unroll
            for (int n = 0; n < 4; ++n) {
                int col = n0 + wc*64 + n*16 + ccol;
                float val = acc[m][n][rr] + bias[col];
                if (EPI == 0) {
                    C[(size_t)row*N + col] = (OutT)__float2bfloat16(val);
                } else {
                    ((float*)C)[(size_t)row*N + col] += gate[(size_t)bi*4608 + col] * val;
                }
            }
        }
    }
}

// ------- bf16 MFMA GEMM 64x128 tile (higher occupancy for N=1152), EPI1 only -------
__global__ __launch_bounds__(256) void k_gemm64(
        const __hip_bfloat16* __restrict__ A,
        const __hip_bfloat16* __restrict__ Wt,
        const float* __restrict__ bias,
        float* __restrict__ C, int M, int N, int K,
        const float* __restrict__ gate) {
    __shared__ __hip_bfloat16 Asm[64*64];
    __shared__ __hip_bfloat16 Bsm[128*64];
    int tid = threadIdx.x;
    int lane = tid & 63, w = tid >> 6;
    int wr = w >> 1, wc = w & 1;
    int m0 = blockIdx.y * 64, n0 = blockIdx.x * 128;
    f32x4 acc[2][4] = {};
    int lr = lane >> 3, ls = lane & 7;
    int swz = ls ^ (lr & 7);
    int x7 = lane & 7;
    const __hip_bfloat16* Ag = A  + (size_t)(m0 + lr)*K + swz*8;
    const __hip_bfloat16* Bg = Wt + (size_t)(n0 + lr)*K + swz*8;
    for (int k0 = 0; k0 < K; k0 += 64) {
        #pragma unroll
        for (int i = 0; i < 2; ++i) {
            int seg = w*2 + i;
            gload16(Ag + (size_t)(seg*8)*K + k0, (char*)Asm + seg*1024);
        }
        #pragma unroll
        for (int i = 0; i < 4; ++i) {
            int seg = w*4 + i;
            gload16(Bg + (size_t)(seg*8)*K + k0, (char*)Bsm + seg*1024);
        }
        __syncthreads();
        #pragma unroll
        for (int kk = 0; kk < 2; ++kk) {
            bf16x8 af[2], bfr[4];
            #pragma unroll
            for (int m = 0; m < 2; ++m) {
                int row = wr*32 + m*16 + (lane&15);
                af[m] = *(const bf16x8*)(Asm + row*64 + (((kk*4 + (lane>>4)) ^ x7) * 8));
            }
            #pragma unroll
            for (int n = 0; n < 4; ++n) {
                int col = wc*64 + n*16 + (lane&15);
                bfr[n] = *(const bf16x8*)(Bsm + col*64 + (((kk*4 + (lane>>4)) ^ x7) * 8));
            }
            #pragma unroll
            for (int m = 0; m < 2; ++m)
                #pragma unroll
                for (int n = 0; n < 4; ++n)
                    acc[m][n] = __builtin_amdgcn_mfma_f32_16x16x32_bf16(af[m], bfr[n], acc[m][n], 0, 0, 0);
        }
        __syncthreads();
    }
    int r0 = (lane >> 4) * 4;
    int ccol = lane & 15;
    #pragma unroll
    for (int m = 0; m < 2; ++m) {
        #pragma unroll
        for (int rr = 0; rr < 4; ++rr) {
            int row = m0 + wr*32 + m*16 + r0 + rr;
            int bi = row >> 10;
            #pragma unroll
            for (int n = 0; n < 4; ++n) {
                int col = n0 + wc*64 + n*16 + ccol;
                float val = acc[m][n][rr] + bias[col];
                C[(size_t)row*N + col] += gate[(size_t)bi*4608 + col] * val;
            }
        }
    }
}

// ------- qkv split + RoPE: qkv (B,L,3456) bf16 -> q,k (B,NH,L,72); v TRANSPOSED (B,NH,72,L) -------
__global__ __launch_bounds__(256) void k_ropesplit(const __hip_bfloat16* __restrict__ qkv,
        const float* __restrict__ cosb, const float* __restrict__ sinb,
        __hip_bfloat16* __restrict__ q, __hip_bfloat16* __restrict__ k,
        __hip_bfloat16* __restrict__ v) {
    int idx = blockIdx.x*256 + threadIdx.x;   // B*NH*L*36
    if (idx >= 2*NHEAD*LTOK*36) return;
    int dp = idx % 36;
    int l  = (idx / 36) % LTOK;
    int h  = (idx / (36*LTOK)) % NHEAD;
    int b  = idx / (36*LTOK*NHEAD);
    int d0 = dp*2;
    size_t src = (size_t)(b*LTOK + l)*3456 + h*HDIM + d0;
    float qe = __bfloat162float(qkv[src]),        qo = __bfloat162float(qkv[src+1]);
    float ke = __bfloat162float(qkv[src+HIDN]),   ko = __bfloat162float(qkv[src+HIDN+1]);
    float ce = cosb[l*HDIM+d0], co = cosb[l*HDIM+d0+1];
    float se = sinb[l*HDIM+d0], so = sinb[l*HDIM+d0+1];
    size_t dst = (size_t)((b*NHEAD + h)*LTOK + l)*HDIM + d0;
    q[dst]   = __float2bfloat16(qe*ce - qo*se);
    q[dst+1] = __float2bfloat16(qo*co + qe*so);
    k[dst]   = __float2bfloat16(ke*ce - ko*se);
    k[dst+1] = __float2bfloat16(ko*co + ke*so);
    size_t vdst = ((size_t)(b*NHEAD + h)*HDIM + d0)*LTOK + l;
    v[vdst]        = qkv[src+2*HIDN];
    v[vdst+LTOK]   = qkv[src+2*HIDN+1];
}

// ------- MFMA flash attention v2: dbuf LDS + global_load_lds + swizzled V ----------
// block = 64 q-rows of one head, 4 waves x 16 rows; KV tile = 64 keys.
// K LDS: [64][72] linear (stride 144B -> 2-way = free). V LDS: [72 d][64 key]
// stride 64 with XOR swizzle (phys col = logical ^ 8*(row&7)) applied on BOTH the
// pre-swizzled global source and the fragment read (rule #21).
// Pipeline: stage(kt+1) issued BEFORE compute(kt); single barrier per tile drains.
__global__ __launch_bounds__(256) void k_attn_mfma(
        const __hip_bfloat16* __restrict__ q,
        const __hip_bfloat16* __restrict__ k,
        const __hip_bfloat16* __restrict__ vt,
        __hip_bfloat16* __restrict__ o) {
    int blk = blockIdx.x;          // B*NH*16 = 512
    int qt = blk & 15, h = (blk >> 4) & 15, b = blk >> 8;
    const float scale = 0.117851130f;   // 1/sqrt(72)
    __shared__ __hip_bfloat16 Ksm[2][64*72];
    __shared__ __hip_bfloat16 Vsm[2][72*64];
    __shared__ __hip_bfloat16 Psm[4][16*72];
    int tid = threadIdx.x, lane = tid & 63, w = tid >> 6;
    int l15 = lane & 15, g = lane >> 4;
    const __hip_bfloat16* qg = q  + ((size_t)(b*NHEAD + h)*LTOK + qt*64)*HDIM;
    const __hip_bfloat16* kg = k  + (size_t)(b*NHEAD + h)*LTOK*HDIM;
    const __hip_bfloat16* vg = vt + (size_t)(b*NHEAD + h)*HDIM*LTOK;
    const bf16x8 z = {};

    // Q fragments straight from global (once)
    bf16x8 qf[3];
    {
        const __hip_bfloat16* qrow = qg + (w*16 + l15)*HDIM;
        qf[0] = *(const bf16x8*)(qrow + g*8);
        qf[1] = *(const bf16x8*)(qrow + 32 + g*8);
        qf[2] = (g == 0) ? *(const bf16x8*)(qrow + 64) : z;
    }
    int vsw  = ((lane & 7) ^ (lane >> 3)) * 8;  // pre-swizzled V source col block
    int vrow = lane >> 3;                        // row within an 8-row segment

    f32x4 oacc[5] = {};
    float mold[4] = {-1e30f, -1e30f, -1e30f, -1e30f};
    float lsum[4] = {};

    // stage tile 0 into buf 0
    {
        const __hip_bfloat16* ktg = kg;
        const __hip_bfloat16* vtg = vg;
        for (int s = w; s < 9; s += 4) {
            gload16(ktg + s*512 + lane*8, (char*)&Ksm[0][0] + s*1024);
            gload16(vtg + (size_t)(s*8 + vrow)*LTOK + vsw, (char*)&Vsm[0][0] + s*1024);
        }
    }
    __syncthreads();

    for (int kt2 = 0; kt2 < 16; ++kt2) {
        int cur = kt2 & 1;
        if (kt2 < 15) {   // issue next-tile DMA before compute; lands under MFMA
            const __hip_bfloat16* ktg = kg + (size_t)(kt2+1)*64*HDIM;
            const __hip_bfloat16* vtg = vg + (kt2+1)*64;
            for (int s = w; s < 9; s += 4) {
                gload16(ktg + s*512 + lane*8, (char*)&Ksm[cur^1][0] + s*1024);
                gload16(vtg + (size_t)(s*8 + vrow)*LTOK + vsw, (char*)&Vsm[cur^1][0] + s*1024);
            }
        }
        const __hip_bfloat16* Kc = Ksm[cur];
        const __hip_bfloat16* Vc = Vsm[cur];
        // S = Q(16x72) @ K^T: 4 key-subtiles x (2 full + 1 partial k-chunk)
        f32x4 st[4] = {};
        __builtin_amdgcn_s_setprio(1);
        #pragma unroll
        for (int t = 0; t < 4; ++t) {
            const __hip_bfloat16* krow = Kc + (t*16 + l15)*72;
            bf16x8 kf0 = *(const bf16x8*)(krow + g*8);
            bf16x8 kf1 = *(const bf16x8*)(krow + 32 + g*8);
            bf16x8 kf2 = (g == 0) ? *(const bf16x8*)(krow + 64) : z;
            st[t] = __builtin_amdgcn_mfma_f32_16x16x32_bf16(qf[0], kf0, st[t], 0, 0, 0);
            st[t] = __builtin_amdgcn_mfma_f32_16x16x32_bf16(qf[1], kf1, st[t], 0, 0, 0);
            st[t] = __builtin_amdgcn_mfma_f32_16x16x32_bf16(qf[2], kf2, st[t], 0, 0, 0);
        }
        __builtin_amdgcn_s_setprio(0);
        // online softmax (row r of wave tile lives in reg r across 16-lane group g)
        #pragma unroll
        for (int r = 0; r < 4; ++r) {
            float mt = fmaxf(fmaxf(st[0][r], st[1][r]), fmaxf(st[2][r], st[3][r]));
            mt = fmaxf(mt, __shfl_xor(mt, 1));
            mt = fmaxf(mt, __shfl_xor(mt, 2));
            mt = fmaxf(mt, __shfl_xor(mt, 4));
            mt = fmaxf(mt, __shfl_xor(mt, 8));
            float mn = fmaxf(mold[r], mt);
            float corr = __expf((mold[r] - mn) * scale);
            mold[r] = mn;
            lsum[r] *= corr;
            #pragma unroll
            for (int dt = 0; dt < 5; ++dt) oacc[dt][r] *= corr;
            float rs = 0.f;
            #pragma unroll
            for (int t = 0; t < 4; ++t) {
                float p = __expf((st[t][r] - mn) * scale);
                rs += p;
                Psm[w][(g*4 + r)*72 + t*16 + l15] = __float2bfloat16(p);
            }
            rs += __shfl_xor(rs, 1);
            rs += __shfl_xor(rs, 2);
            rs += __shfl_xor(rs, 4);
            rs += __shfl_xor(rs, 8);
            lsum[r] += rs;
        }
        // O += P(16x64) @ V(64x80): 5 d-subtiles x 2 k-chunks, swizzled V reads
        bf16x8 pa0 = *(const bf16x8*)(&Psm[w][l15*72 + g*8]);
        bf16x8 pa1 = *(const bf16x8*)(&Psm[w][l15*72 + 32 + g*8]);
        int cswz = (l15 & 7)*8;
        __builtin_amdgcn_s_setprio(1);
        #pragma unroll
        for (int dt = 0; dt < 5; ++dt) {
            int row = dt*16 + l15;
            bool valid = (dt < 4) | (l15 < 8);
            bf16x8 vf0 = valid ? *(const bf16x8*)(Vc + row*64 + ((g*8) ^ cswz)) : z;
            bf16x8 vf1 = valid ? *(const bf16x8*)(Vc + row*64 + ((32 + g*8) ^ cswz)) : z;
            oacc[dt] = __builtin_amdgcn_mfma_f32_16x16x32_bf16(pa0, vf0, oacc[dt], 0, 0, 0);
            oacc[dt] = __builtin_amdgcn_mfma_f32_16x16x32_bf16(pa1, vf1, oacc[dt], 0, 0, 0);
        }
        __builtin_amdgcn_s_setprio(0);
        __syncthreads();   // drains DMA for buf^1 + protects Ksm/Vsm reuse
    }
    #pragma unroll
    for (int r = 0; r < 4; ++r) {
        float inv = 1.f / lsum[r];
        int row = qt*64 + w*16 + g*4 + r;
        __hip_bfloat16* op = o + ((size_t)b*LTOK + row)*HIDN + h*HDIM;
        #pragma unroll
        for (int dt = 0; dt < 5; ++dt) {
            int d = dt*16 + l15;
            if (d < HDIM) op[d] = __float2bfloat16(oacc[dt][r] * inv);
        }
    }
}

// ---------------- gated linear unit: mh = silu(x1)*x2, bf16x8 vectorized ----------------
__global__ __launch_bounds__(256) void k_glu(const __hip_bfloat16* __restrict__ x12,
        __hip_bfloat16* __restrict__ mh) {
    int idx = blockIdx.x*256 + threadIdx.x;   // 2048*384
    int m = idx / 384, jj = (idx % 384)*8;
    bf16x8 v1 = *(const bf16x8*)(x12 + (size_t)m*6144 + jj);
    bf16x8 v2 = *(const bf16x8*)(x12 + (size_t)m*6144 + MLPM + jj);
    bf16x8 ov;
    #pragma unroll
    for (int i = 0; i < 8; ++i) {
        short s1 = v1[i], s2 = v2[i];
        float x1 = __bfloat162float(*(__hip_bfloat16*)&s1);
        float x2 = __bfloat162float(*(__hip_bfloat16*)&s2);
        __hip_bfloat16 r = __float2bfloat16(x1 / (1.f + __expf(-x1)) * x2);
        ov[i] = *(short*)&r;
    }
    *(bf16x8*)(mh + (size_t)m*MLPM + jj) = ov;
}

// ---------------- final norm + linear + unpatchify ----------------
__global__ __launch_bounds__(256) void k_final(const float* __restrict__ hx,
        const float* __restrict__ fnw, const float* __restrict__ fmod,
        const float* __restrict__ flw, const float* __restrict__ flb,
        float* __restrict__ out) {
    int m = blockIdx.x; int b = m >> 10, l = m & 1023;
    int tid = threadIdx.x;
    const float* row = hx + (size_t)m*HIDN;
    float part = 0.f;
    for (int j = tid; j < HIDN; j += 256) { float v2 = row[j]; part += v2*v2; }
    for (int off = 32; off; off >>= 1) part += __shfl_xor(part, off);
    __shared__ float wsum[4];
    __shared__ float hfs[HIDN];
    __shared__ float red[4][16];
    if ((tid & 63) == 0) wsum[tid >> 6] = part;
    __syncthreads();
    float rs = rsqrtf((wsum[0]+wsum[1]+wsum[2]+wsum[3]) * (1.f/HIDN) + 1e-6f);
    const float* fm = fmod + (size_t)b*2304;
    for (int j = tid; j < HIDN; j += 256)
        hfs[j] = row[j] * rs * fnw[j] * (1.f + fm[HIDN + j]) + fm[j];
    __syncthreads();
    float pacc[16] = {};
    for (int j = tid; j < HIDN; j += 256) {
        float hv = hfs[j];
        #pragma unroll
        for (int kk = 0; kk < 16; ++kk) pacc[kk] += hv * flw[j*16 + kk];
    }
    #pragma unroll
    for (int kk = 0; kk < 16; ++kk)
        for (int off = 32; off; off >>= 1) pacc[kk] += __shfl_xor(pacc[kk], off);
    if ((tid & 63) == 0) {
        int w = tid >> 6;
        #pragma unroll
        for (int kk = 0; kk < 16; ++kk) red[w][kk] = pacc[kk];
    }
    __syncthreads();
    if (tid < 16) {
        float val = red[0][tid] + red[1][tid] + red[2][tid] + red[3][tid] + flb[tid];
        int pi = tid >> 3, pj = (tid >> 2) & 1, c = tid & 3;
        int si = l >> 5, sj = l & 31;
        out[((size_t)(b*4 + c)*64 + si*2 + pi)*64 + sj*2 + pj] = val;
    }
}

extern "C" void kernel_launch(void* const* d_in, const int* in_sizes, int n_in,
                              void* d_out, int out_size, void* d_ws, size_t ws_size,
                              hipStream_t stream) {
    const float* x        = (const float*)d_in[0];
    const float* t        = (const float*)d_in[1];
    const int*   y        = (const int*)  d_in[2];
    const float* patch_w  = (const float*)d_in[3];
    const float* patch_b  = (const float*)d_in[4];
    const float* t_w1     = (const float*)d_in[5];
    const float* t_b1     = (const float*)d_in[6];
    const float* t_w2     = (const float*)d_in[7];
    const float* t_b2     = (const float*)d_in[8];
    const float* y_table  = (const float*)d_in[9];
    const float* norm1_w  = (const float*)d_in[10];
    const float* qkv_w    = (const float*)d_in[11];
    const float* qkv_b    = (const float*)d_in[12];
    const float* out_w    = (const float*)d_in[13];
    const float* out_b    = (const float*)d_in[14];
    const float* norm2_w  = (const float*)d_in[15];
    const float* mlp_w12  = (const float*)d_in[16];
    const float* mlp_b12  = (const float*)d_in[17];
    const float* mlp_w3   = (const float*)d_in[18];
    const float* mlp_b3   = (const float*)d_in[19];
    const float* adaln_w  = (const float*)d_in[20];
    const float* adaln_b  = (const float*)d_in[21];
    const float* fnorm_w  = (const float*)d_in[22];
    const float* fadaln_w = (const float*)d_in[23];
    const float* fadaln_b = (const float*)d_in[24];
    const float* flin_w   = (const float*)d_in[25];
    const float* flin_b   = (const float*)d_in[26];

    char* base = (char*)d_ws;
    float*          hx    = (float*)(base);                       //  9,437,184 B
    __hip_bfloat16* qkvbf = (__hip_bfloat16*)(base +  9437184);   // 25,165,824 B (qkv & x12)
    __hip_bfloat16* qbf   = (__hip_bfloat16*)(base + 34603008);   //  4,718,592 B
    __hip_bfloat16* kbf   = (__hip_bfloat16*)(base + 39321600);   //  4,718,592 B
    __hip_bfloat16* vbf   = (__hip_bfloat16*)(base + 44040192);   //  4,718,592 B (B,NH,72,L)
    __hip_bfloat16* hbf   = (__hip_bfloat16*)(base + 48758784);   //  4,718,592 B
    __hip_bfloat16* mhbf  = qbf;                                  // aliases q/k/v (consumed)
    __hip_bfloat16* wtb   = (__hip_bfloat16*)(base + 53477376);   // 31,850,496 B
    float* temb1 = (float*)(base + 85327872);        // 9216 B
    float* csilu = (float*)(base + 85337088);        // 9216 B
    float* modb  = (float*)(base + 85346304);        // 147456 B [4][2][4608]
    float* fmod  = (float*)(base + 85493760);        // 18432 B  [2][2304]
    float* cosb  = (float*)(base + 85512192);        // 294912 B
    float* sinb  = (float*)(base + 85807104);        // 294912 B
    float* condp = (float*)(base + 86102016);        // 663552 B [4][2][20736]
    float* csilup= (float*)(base + 86765568);        // 36864 B  [4][2][1152]
    // total 86,802,432 B = 86.8 MB

    __hip_bfloat16* wt_qkv = wtb;                        // [3456][1152]
    __hip_bfloat16* wt_out = wt_qkv + 3456*1152;         // [1152][1152]
    __hip_bfloat16* wt_m12 = wt_out + 1152*1152;         // [6144][1152]
    __hip_bfloat16* wt_m3  = wt_m12 + 6144*1152;         // [1152][3072]

    k_patch<<<2048, 256, 0, stream>>>(x, patch_w, patch_b, hx);
    k_temb1_v2<<<dim3(9,2), 256, 0, stream>>>(t, t_w1, t_b1, temb1);
    k_csilu_s1<<<dim3(9,4), 256, 0, stream>>>(temb1, t_w2, csilup);
    k_csilu_s2<<<dim3(9,2), 128, 0, stream>>>(csilup, t_b2, y_table, y, csilu);
    k_cond_s1<<<dim3(162,4), 256, 0, stream>>>(csilu, adaln_w, fadaln_w, condp);
    k_cond_s2<<<dim3(81,2), 256, 0, stream>>>(condp, adaln_b, fadaln_b, modb, fmod);
    k_rope<<<288, 256, 0, stream>>>(cosb, sinb);

    for (int d = 0; d < 4; ++d) {
        const float* modd = modb + (size_t)d*2*4608;
        k_castT<<<dim3(108,36), dim3(32,8), 0, stream>>>(qkv_w  + (size_t)d*HIDN*3456, wt_qkv, HIDN, 3456);
        k_castT<<<dim3( 36,36), dim3(32,8), 0, stream>>>(out_w  + (size_t)d*HIDN*HIDN, wt_out, HIDN, HIDN);
        k_castT<<<dim3(192,36), dim3(32,8), 0, stream>>>(mlp_w12+ (size_t)d*HIDN*6144, wt_m12, HIDN, 6144);
        k_castT<<<dim3( 36,96), dim3(32,8), 0, stream>>>(mlp_w3 + (size_t)d*MLPM*HIDN, wt_m3,  MLPM, HIDN);

        k_rms<<<2048, 256, 0, stream>>>(hx, norm1_w + d*HIDN, modd + 0*HIDN, hbf);
        k_gemm_bf16<0, __hip_bfloat16><<<dim3(27,16), 256, 0, stream>>>(hbf, wt_qkv,
                qkv_b + d*3456, qkvbf, MTOK, 3456, HIDN, nullptr);
        k_ropesplit<<<4608, 256, 0, stream>>>(qkvbf, cosb, sinb, qbf, kbf, vbf);
        k_attn_mfma<<<512, 256, 0, stream>>>(qbf, kbf, vbf, hbf);
        k_gemm64<<<dim3(9,32), 256, 0, stream>>>(hbf, wt_out,
                out_b + d*HIDN, hx, MTOK, HIDN, HIDN, modd + 1*HIDN);
        k_rms<<<2048, 256, 0, stream>>>(hx, norm2_w + d*HIDN, modd + 2*HIDN, hbf);
        k_gemm_bf16<0, __hip_bfloat16><<<dim3(48,16), 256, 0, stream>>>(hbf, wt_m12,
                mlp_b12 + d*6144, qkvbf, MTOK, 6144, HIDN, nullptr);
        k_glu<<<3072, 256, 0, stream>>>(qkvbf, mhbf);
        k_gemm64<<<dim3(9,32), 256, 0, stream>>>(mhbf, wt_m3,
                mlp_b3 + d*HIDN, hx, MTOK, HIDN, MLPM, modd + 3*HIDN);
    }
    k_final<<<2048, 256, 0, stream>>>(hx, fnorm_w, fmod, flin_w, flin_b, (float*)d_out);
}